// Round 1
// baseline (6046.703 us; speedup 1.0000x reference)
//
#include <hip/hip_runtime.h>
#include <hip/hip_bf16.h>

typedef unsigned short u16;
typedef __attribute__((ext_vector_type(8))) short short8;   // 8 x bf16 (4 VGPRs)
typedef __attribute__((ext_vector_type(4))) float f32x4;

// ---------------- helpers ----------------
__device__ __forceinline__ u16 f2bf(float f){
  union { float fv; unsigned int u; } v; v.fv = f;
  unsigned int u = v.u;
  u = u + 0x7FFFu + ((u >> 16) & 1u);   // RNE
  return (u16)(u >> 16);
}
__device__ __forceinline__ float bf2f(u16 h){
  union { unsigned int u; float fv; } v; v.u = ((unsigned int)h) << 16; return v.fv;
}
__device__ __forceinline__ float sigmoidf_(float x){ return 1.f/(1.f + __expf(-x)); }
__device__ __forceinline__ float tanhf_(float x){ return 2.f/(1.f + __expf(-2.f*x)) - 1.f; }

__device__ __forceinline__ void gload16(const void* g, void* l){
  __builtin_amdgcn_global_load_lds(
      (const __attribute__((address_space(1))) void*)g,
      (__attribute__((address_space(3))) void*)l, 16, 0, 0);
}
__device__ __forceinline__ f32x4 mfma_bf16(short8 a, short8 b, f32x4 c){
  return __builtin_amdgcn_mfma_f32_16x16x32_bf16(a, b, c, 0, 0, 0);
}

// ---------------- workspace layout (bytes) ----------------
// peak ~443 MB with lifetime aliasing
constexpr size_t OFF_A    = 0;                       // R bf16 [32][512][64][32] ; later: attn-out bf16 [16384][2048]
constexpr size_t OFF_B    = 67108864;                // y_seq bf16 [16384][2048]
constexpr size_t OFF_C    = OFF_B + 67108864;        // QKV bf16 [16384][6144] ; later: GI f32 + OUTF f32
constexpr size_t OFF_D    = OFF_C + 201326592;       // ctx bf16 [16384][2048] ; later: h_ln bf16
constexpr size_t OFF_E    = OFF_D + 67108864;        // WqkvT bf16 [6144][2048]
constexpr size_t OFF_WFT  = OFF_E + 25165824;        // WfT bf16 [2048][2048]
constexpr size_t OFF_WIH  = OFF_WFT + 8388608;       // WihT bf16 [256][2048] (rows 192..255 zero)
constexpr size_t OFF_LHAT = OFF_WIH + 1048576;       // Lhat f32 [32][64][64]
constexpr size_t OFF_B1P  = OFF_LHAT + 524288;       // bn1 partials f32 [32][64][32][2]
constexpr size_t OFF_B1S  = OFF_B1P + 524288;        // bn1 scale/shift f32 [32][32][2]
constexpr size_t OFF_B2P  = OFF_B1S + 8192;          // bn2 partials f32 [32][512][32][2]
constexpr size_t OFF_B2S  = OFF_B2P + 4194304;       // bn2 scale/shift f32 [32][32][2]
constexpr size_t OFF_GI   = OFF_C;                   // f32 [16384][256]
constexpr size_t OFF_OUTF = OFF_C + 16777216;        // f32 [512][2048]

// ---------------- weight transpose: W[k][n] f32 -> WT[n][k] bf16 ----------------
__global__ __launch_bounds__(256) void wtrans_kernel(const float* __restrict__ Wq, const float* __restrict__ Wk,
                                                     const float* __restrict__ Wv, const float* __restrict__ Wf,
                                                     u16* __restrict__ WqkvT, u16* __restrict__ WfT)
{
  const int k0 = blockIdx.x*64, n0 = blockIdx.y*64, z = blockIdx.z;
  const float* src = (z==0)?Wq:(z==1)?Wk:(z==2)?Wv:Wf;
  u16* dst = (z<3) ? (WqkvT + (size_t)z*2048*2048) : WfT;
  __shared__ float tile[64][65];
  const int c = threadIdx.x & 63, r0 = threadIdx.x >> 6;
#pragma unroll
  for (int i=0;i<16;++i){ int r = r0 + i*4; tile[r][c] = src[(size_t)(k0+r)*2048 + n0 + c]; }
  __syncthreads();
#pragma unroll
  for (int i=0;i<16;++i){ int r = r0 + i*4; dst[(size_t)(n0+r)*2048 + k0 + c] = f2bf(tile[c][r]); }
}

__global__ __launch_bounds__(256) void wih_kernel(const float* __restrict__ Wih, u16* __restrict__ WT)
{
  const int row = blockIdx.x, tid = threadIdx.x;
#pragma unroll
  for (int i=0;i<8;++i){ int col = tid + i*256;
    float v = (row < 192) ? Wih[(size_t)row*2048 + col] : 0.f;
    WT[(size_t)row*2048 + col] = f2bf(v);
  }
}

// ---------------- BN1 stats (two-stage, deterministic) ----------------
__global__ __launch_bounds__(256) void bn1_part_kernel(const float* __restrict__ x, float* __restrict__ part)
{
  const int t = blockIdx.x, sl = blockIdx.y;
  const int f = threadIdx.x & 31, grp = threadIdx.x >> 5;
  float s = 0.f, ss = 0.f;
  for (int bb = 0; bb < 8; ++bb){
    const int b = sl*8 + bb;
    const float* xp = x + ((size_t)(b*32 + t))*2048;
    for (int i = 0; i < 8; ++i){
      int n = i*8 + grp;
      float v = xp[n*32 + f];
      s += v; ss += v*v;
    }
  }
  __shared__ float red[8][32][2];
  red[grp][f][0] = s; red[grp][f][1] = ss;
  __syncthreads();
  if (threadIdx.x < 32){
    float S=0, SS=0;
    for (int g=0; g<8; ++g){ S += red[g][threadIdx.x][0]; SS += red[g][threadIdx.x][1]; }
    size_t o = (((size_t)t*64 + sl)*32 + threadIdx.x)*2;
    part[o] = S; part[o+1] = SS;
  }
}

__global__ __launch_bounds__(256) void bn1_fin_kernel(const float* __restrict__ part, const float* __restrict__ g1,
                                                      const float* __restrict__ b1, float* __restrict__ out)
{
  const int t = blockIdx.x;
  const int f = threadIdx.x & 31, grp = threadIdx.x >> 5;
  float s=0, ss=0;
  for (int sl = grp; sl < 64; sl += 8){
    size_t o = (((size_t)t*64 + sl)*32 + f)*2;
    s += part[o]; ss += part[o+1];
  }
  __shared__ float red[8][32][2];
  red[grp][f][0]=s; red[grp][f][1]=ss;
  __syncthreads();
  if (threadIdx.x < 32){
    float S=0, SS=0;
    for (int g=0; g<8; ++g){ S+=red[g][threadIdx.x][0]; SS+=red[g][threadIdx.x][1]; }
    float mean = S*(1.f/32768.f);
    float var  = SS*(1.f/32768.f) - mean*mean;
    float sc   = g1[t*32+threadIdx.x]*rsqrtf(var + 1e-5f);
    out[(t*32+threadIdx.x)*2]   = sc;
    out[(t*32+threadIdx.x)*2+1] = b1[t*32+threadIdx.x] - mean*sc;
  }
}

// ---------------- per-t rescaled Laplacian:  Lhat = -D^-1/2 (relu(A)od + relu(A)od^T) D^-1/2 ----------------
__global__ __launch_bounds__(256) void lap_kernel(const float* __restrict__ A, float* __restrict__ Lhat)
{
  const int t = blockIdx.x, tid = threadIdx.x;
  __shared__ float Ar[64][65];
  __shared__ float dr[64];
#pragma unroll
  for (int i=0;i<16;++i){ int idx = tid + i*256; int r = idx>>6, c = idx&63;
    float v = A[(size_t)t*4096 + idx]; v = fmaxf(v, 0.f); if (r==c) v = 0.f;
    Ar[r][c] = v; }
  __syncthreads();
  if (tid < 64){
    float s = 0;
    for (int c2=0;c2<64;++c2) s += Ar[tid][c2] + Ar[c2][tid];
    dr[tid] = rsqrtf(s + 1e-10f);
  }
  __syncthreads();
#pragma unroll
  for (int i=0;i<16;++i){ int idx = tid + i*256; int r = idx>>6, c = idx&63;
    Lhat[(size_t)t*4096 + idx] = -(Ar[r][c] + Ar[c][r]) * dr[r] * dr[c];
  }
}

// ---------------- Chebyshev conv (recurrence on X) + relu + bn2 partials ----------------
__global__ __launch_bounds__(256) void cheby_kernel(const float* __restrict__ x, const float* __restrict__ Lhat,
                                                    const float* __restrict__ chebW, const float* __restrict__ bn1ss,
                                                    u16* __restrict__ Rb, float* __restrict__ bn2p)
{
  const int t = blockIdx.x >> 9, b = blockIdx.x & 511, tid = threadIdx.x;
  __shared__ float Ls[64][65];
  __shared__ float Ws[4][32][33];
  __shared__ float Xa[64][33];
  __shared__ float Xb[64][33];
  __shared__ float red[8][32][2];
  const int o = tid & 31, grp = tid >> 5, g8 = grp*8;
#pragma unroll
  for (int i=0;i<16;++i){ int idx = tid + i*256; Ls[idx>>6][idx&63] = Lhat[(size_t)t*4096 + idx]; }
#pragma unroll
  for (int i=0;i<16;++i){ int idx = tid + i*256; Ws[idx>>10][(idx>>5)&31][idx&31] = chebW[(size_t)t*4096 + idx]; }
  const float sc = bn1ss[(t*32+o)*2], sh = bn1ss[(t*32+o)*2+1];
  const float* xrow = x + ((size_t)(b*32 + t))*2048;
  float racc[8];
#pragma unroll
  for (int j=0;j<8;++j){
    racc[j] = 0.f;
    Xa[g8+j][o] = xrow[(g8+j)*32 + o]*sc + sh;   // X0 = bn1(x)
  }
  __syncthreads();
  float xn[8];
  // k=0:  R += X0 @ W0
  for (int ff=0; ff<32; ++ff){ float wv = Ws[0][ff][o];
#pragma unroll
    for (int j=0;j<8;++j) racc[j] += Xa[g8+j][ff]*wv; }
  // X1 = L @ X0  -> Xb
#pragma unroll
  for (int j=0;j<8;++j) xn[j] = 0.f;
  for (int m=0;m<64;++m){ float xv = Xa[m][o];
#pragma unroll
    for (int j=0;j<8;++j) xn[j] += Ls[g8+j][m]*xv; }
#pragma unroll
  for (int j=0;j<8;++j) Xb[g8+j][o] = xn[j];
  __syncthreads();
  // k=1
  for (int ff=0; ff<32; ++ff){ float wv = Ws[1][ff][o];
#pragma unroll
    for (int j=0;j<8;++j) racc[j] += Xb[g8+j][ff]*wv; }
  // X2 = 2 L X1 - X0 -> Xa
#pragma unroll
  for (int j=0;j<8;++j) xn[j] = 0.f;
  for (int m=0;m<64;++m){ float xv = Xb[m][o];
#pragma unroll
    for (int j=0;j<8;++j) xn[j] += Ls[g8+j][m]*xv; }
#pragma unroll
  for (int j=0;j<8;++j){ Xa[g8+j][o] = 2.f*xn[j] - Xa[g8+j][o]; }
  __syncthreads();
  // k=2
  for (int ff=0; ff<32; ++ff){ float wv = Ws[2][ff][o];
#pragma unroll
    for (int j=0;j<8;++j) racc[j] += Xa[g8+j][ff]*wv; }
  // X3 = 2 L X2 - X1 -> Xb
#pragma unroll
  for (int j=0;j<8;++j) xn[j] = 0.f;
  for (int m=0;m<64;++m){ float xv = Xa[m][o];
#pragma unroll
    for (int j=0;j<8;++j) xn[j] += Ls[g8+j][m]*xv; }
#pragma unroll
  for (int j=0;j<8;++j){ Xb[g8+j][o] = 2.f*xn[j] - Xb[g8+j][o]; }
  __syncthreads();
  // k=3
  for (int ff=0; ff<32; ++ff){ float wv = Ws[3][ff][o];
#pragma unroll
    for (int j=0;j<8;++j) racc[j] += Xb[g8+j][ff]*wv; }

  // relu, write R (bf16), bn2 partial sums over n
  float s = 0.f, ss2 = 0.f;
#pragma unroll
  for (int j=0;j<8;++j){
    float r = fmaxf(racc[j], 0.f);
    racc[j] = r; s += r; ss2 += r*r;
  }
  u16* rrow = Rb + ((size_t)(t*512+b))*2048;
#pragma unroll
  for (int j=0;j<8;++j) rrow[(g8+j)*32 + o] = f2bf(racc[j]);
  red[grp][o][0] = s; red[grp][o][1] = ss2;
  __syncthreads();
  if (tid < 32){
    float S=0, SS=0;
#pragma unroll
    for (int g=0; g<8; ++g){ S += red[g][tid][0]; SS += red[g][tid][1]; }
    size_t off = ((size_t)(t*512+b)*32 + tid)*2;
    bn2p[off] = S; bn2p[off+1] = SS;
  }
}

__global__ __launch_bounds__(256) void bn2_fin_kernel(const float* __restrict__ part, const float* __restrict__ g2,
                                                      const float* __restrict__ b2, float* __restrict__ out)
{
  const int t = blockIdx.x;
  const int f = threadIdx.x & 31, grp = threadIdx.x >> 5;
  float s=0, ss=0;
  for (int b = grp; b < 512; b += 8){
    size_t o = ((size_t)(t*512+b)*32 + f)*2;
    s += part[o]; ss += part[o+1];
  }
  __shared__ float red[8][32][2];
  red[grp][f][0]=s; red[grp][f][1]=ss;
  __syncthreads();
  if (threadIdx.x < 32){
    float S=0, SS=0;
    for (int g=0; g<8; ++g){ S+=red[g][threadIdx.x][0]; SS+=red[g][threadIdx.x][1]; }
    float mean = S*(1.f/32768.f);
    float var  = SS*(1.f/32768.f) - mean*mean;
    float scv  = g2[t*32+threadIdx.x]*rsqrtf(var + 1e-5f);
    out[(t*32+threadIdx.x)*2]   = scv;
    out[(t*32+threadIdx.x)*2+1] = b2[t*32+threadIdx.x] - mean*scv;
  }
}

// ---------------- BN2 apply + sigmoid + torch stack/transpose/reshape permute ----------------
// y_seq[b, n>>1, (n&1)*1024 + t*32 + f] = sigmoid(bn2(R[t,b,n,f]))
__global__ __launch_bounds__(256) void bn2apply_kernel(const u16* __restrict__ Rb, const float* __restrict__ ss,
                                                       u16* __restrict__ YS)
{
  const int t = blockIdx.x >> 9, b = blockIdx.x & 511, tid = threadIdx.x;
  __shared__ float scs[64];
  if (tid < 64) scs[tid] = ss[t*64 + tid];
  __syncthreads();
  const int n = tid >> 2, f0 = (tid & 3) << 3;
  short8 rv = *(const short8*)&Rb[((size_t)(t*512+b))*2048 + tid*8];
  short8 w;
#pragma unroll
  for (int e=0;e<8;++e){
    int f = f0 + e;
    float v = bf2f((u16)rv[e])*scs[f*2] + scs[f*2+1];
    w[e] = (short)f2bf(sigmoidf_(v));
  }
  *(short8*)&YS[((size_t)(b*32 + (n>>1)))*2048 + (n&1)*1024 + t*32 + f0] = w;
}

// ---------------- bf16 MFMA GEMM: C[M,N] = A[M,K] * BT[N,K]^T  (m97 structure) ----------------
template<int CB>   // 0 -> bf16 C, 1 -> f32 C
__global__ __launch_bounds__(256) void gemm_bt_kernel(const u16* __restrict__ A, const u16* __restrict__ BT,
                                                      void* __restrict__ C, int M, int N, int K)
{
  __shared__ u16 As[128*32];
  __shared__ u16 Bs[128*32];
  const int tid = threadIdx.x;
  const int wave = tid >> 6, lane = tid & 63;
  const int mblocks = M >> 7;
  const int mb = blockIdx.x % mblocks;
  const int nb = blockIdx.x / mblocks;
  const int lr = lane >> 2;
  const int lc = (lane & 3) << 3;
  const u16* Ag0 = A  + (size_t)(mb*128 + wave*16 + lr)*K + lc;
  const u16* Bg0 = BT + (size_t)(nb*128 + wave*16 + lr)*K + lc;
  const u16* Ag1 = Ag0 + (size_t)64*K;
  const u16* Bg1 = Bg0 + (size_t)64*K;
  u16* lA0 = &As[(wave*16)*32];
  u16* lA1 = &As[(wave*16+64)*32];
  u16* lB0 = &Bs[(wave*16)*32];
  u16* lB1 = &Bs[(wave*16+64)*32];
  const int wm = (wave >> 1)*64, wn = (wave & 1)*64;
  const int fr = lane & 15, fk = (lane >> 4) << 3;
  f32x4 acc[4][4] = {};
  for (int kt = 0; kt < K; kt += 32){
    __syncthreads();
    gload16(Ag0 + kt, lA0);
    gload16(Ag1 + kt, lA1);
    gload16(Bg0 + kt, lB0);
    gload16(Bg1 + kt, lB1);
    __syncthreads();
    short8 af[4], bfr[4];
#pragma unroll
    for (int i=0;i<4;++i) af[i]  = *(const short8*)&As[(wm + i*16 + fr)*32 + fk];
#pragma unroll
    for (int j=0;j<4;++j) bfr[j] = *(const short8*)&Bs[(wn + j*16 + fr)*32 + fk];
#pragma unroll
    for (int i=0;i<4;++i)
#pragma unroll
      for (int j=0;j<4;++j)
        acc[i][j] = mfma_bf16(af[i], bfr[j], acc[i][j]);
  }
  const int cr = (lane >> 4) << 2, cc = lane & 15;
#pragma unroll
  for (int i=0;i<4;++i)
#pragma unroll
    for (int j=0;j<4;++j)
#pragma unroll
      for (int r=0;r<4;++r){
        const size_t row = (size_t)(mb*128 + wm + i*16 + cr + r);
        const size_t col = (size_t)(nb*128 + wn + j*16 + cc);
        if (CB == 0) ((u16*)C)[row*(size_t)N + col] = f2bf(acc[i][j][r]);
        else        ((float*)C)[row*(size_t)N + col] = acc[i][j][r];
      }
}

// ---------------- attention: per (b,h) block, T=32, dh=512 ----------------
__global__ __launch_bounds__(256) void attn_kernel(const u16* __restrict__ QKV, u16* __restrict__ CTX)
{
  const int b = blockIdx.x >> 2, h = blockIdx.x & 3;
  const int tid = threadIdx.x;
  const int wave = tid >> 6, lane = tid & 63;
  __shared__ float spart[4][32][33];
  __shared__ float sm[32][33];
  __shared__ float rowinv[32];
  __shared__ u16 pb[32][40];
  __shared__ u16 vt[512][40];   // v^T : vt[d][t2]

  { // stage v^T
    const int t2 = tid >> 3;
    const size_t vbase = ((size_t)(b*32 + t2))*6144 + 4096 + h*512;
#pragma unroll
    for (int i = 0; i < 16; ++i){
      int d = (tid & 7)*64 + i*4;
      const u16* p = &QKV[vbase + d];
      vt[d+0][t2] = p[0]; vt[d+1][t2] = p[1]; vt[d+2][t2] = p[2]; vt[d+3][t2] = p[3];
    }
  }
  // scores partial (wave w handles d in [w*128, w*128+128)), fragments direct from global
  const int fr = lane & 15, fk = (lane >> 4) << 3;
  f32x4 sacc[2][2] = {};
  const size_t qrow = ((size_t)(b*32))*6144 + h*512;
#pragma unroll
  for (int kk = 0; kk < 4; ++kk){
    const int kof = wave*128 + kk*32 + fk;
    short8 qf0 = *(const short8*)&QKV[qrow + (size_t)fr*6144 + kof];
    short8 qf1 = *(const short8*)&QKV[qrow + (size_t)(fr+16)*6144 + kof];
    short8 kf0 = *(const short8*)&QKV[qrow + 2048 + (size_t)fr*6144 + kof];
    short8 kf1 = *(const short8*)&QKV[qrow + 2048 + (size_t)(fr+16)*6144 + kof];
    sacc[0][0] = mfma_bf16(qf0, kf0, sacc[0][0]);
    sacc[0][1] = mfma_bf16(qf0, kf1, sacc[0][1]);
    sacc[1][0] = mfma_bf16(qf1, kf0, sacc[1][0]);
    sacc[1][1] = mfma_bf16(qf1, kf1, sacc[1][1]);
  }
  const int cr = (lane >> 4) << 2, cc = lane & 15;
#pragma unroll
  for (int i=0;i<2;++i)
#pragma unroll
    for (int j=0;j<2;++j)
#pragma unroll
      for (int r=0;r<4;++r) spart[wave][i*16+cr+r][j*16+cc] = sacc[i][j][r];
  __syncthreads();
  const float scl = 0.04419417382415922f;  // 512^-0.5
  for (int e = tid; e < 1024; e += 256){
    int r = e >> 5, c = e & 31;
    sm[r][c] = (spart[0][r][c]+spart[1][r][c]+spart[2][r][c]+spart[3][r][c])*scl;
  }
  __syncthreads();
  if (tid < 32){
    float m = -1e30f;
    for (int c=0;c<32;++c) m = fmaxf(m, sm[tid][c]);
    float s = 0;
    for (int c=0;c<32;++c){ float e = __expf(sm[tid][c]-m); sm[tid][c] = e; s += e; }
    rowinv[tid] = 1.f/s;
  }
  __syncthreads();
  for (int e = tid; e < 1024; e += 256){
    int r = e>>5, c = e&31;
    pb[r][c] = f2bf(sm[r][c]*rowinv[r]);
  }
  __syncthreads();
  // ctx = P @ V : wave w covers d-slice [w*128, +128)
  f32x4 cacc[2][8] = {};
  short8 pf0 = *(const short8*)&pb[fr][fk];
  short8 pf1 = *(const short8*)&pb[fr+16][fk];
#pragma unroll
  for (int j=0;j<8;++j){
    short8 vf = *(const short8*)&vt[wave*128 + j*16 + fr][fk];
    cacc[0][j] = mfma_bf16(pf0, vf, cacc[0][j]);
    cacc[1][j] = mfma_bf16(pf1, vf, cacc[1][j]);
  }
#pragma unroll
  for (int i=0;i<2;++i)
#pragma unroll
    for (int j=0;j<8;++j)
#pragma unroll
      for (int r=0;r<4;++r){
        int t1 = i*16 + cr + r;
        int d  = wave*128 + j*16 + cc;
        CTX[((size_t)(b*32+t1))*2048 + h*512 + d] = f2bf(cacc[i][j][r]);
      }
}

// ---------------- residual + bias + LayerNorm -> h_ln bf16 ----------------
__global__ __launch_bounds__(256) void ln_kernel(const u16* __restrict__ OUT, const u16* __restrict__ YS,
                                                 const float* __restrict__ bfv, const float* __restrict__ lng,
                                                 const float* __restrict__ lnb, u16* __restrict__ HLN)
{
  const int row = blockIdx.x, tid = threadIdx.x;
  const size_t base = (size_t)row*2048 + tid*8;
  short8 o8 = *(const short8*)&OUT[base];
  short8 y8 = *(const short8*)&YS[base];
  float hv[8]; float s = 0;
#pragma unroll
  for (int e=0;e<8;++e){ float v = bf2f((u16)o8[e]) + bf2f((u16)y8[e]) + bfv[tid*8+e]; hv[e]=v; s += v; }
  __shared__ float red[4];
#pragma unroll
  for (int off=32; off; off>>=1) s += __shfl_down(s, off, 64);
  if ((tid&63)==0) red[tid>>6] = s;
  __syncthreads();
  const float mu = (red[0]+red[1]+red[2]+red[3]) * (1.f/2048.f);
  float s2 = 0;
#pragma unroll
  for (int e=0;e<8;++e){ float d = hv[e]-mu; s2 += d*d; }
  __syncthreads();
#pragma unroll
  for (int off=32; off; off>>=1) s2 += __shfl_down(s2, off, 64);
  if ((tid&63)==0) red[tid>>6] = s2;
  __syncthreads();
  const float rstd = rsqrtf((red[0]+red[1]+red[2]+red[3])*(1.f/2048.f) + 1e-5f);
  short8 w;
#pragma unroll
  for (int e=0;e<8;++e) w[e] = (short)f2bf((hv[e]-mu)*rstd*lng[tid*8+e] + lnb[tid*8+e]);
  *(short8*)&HLN[base] = w;
}

// ---------------- GRU scan (per-batch-row independent) ----------------
__global__ __launch_bounds__(256) void gru_kernel(const float* __restrict__ GI, const float* __restrict__ Whh,
                                                  const float* __restrict__ bih, const float* __restrict__ bhh,
                                                  float* __restrict__ OUTF)
{
  const int b = blockIdx.x, tid = threadIdx.x;
  __shared__ float w[192*65];
  __shared__ float hprev[64];
  __shared__ float gh[192];
#pragma unroll
  for (int i=0;i<48;++i){ int idx = tid + i*256; w[(idx>>6)*65 + (idx&63)] = Whh[idx]; }
  if (tid < 64) hprev[tid] = 0.f;
  const float bh_ = (tid<192) ? bhh[tid] : 0.f;
  __syncthreads();
  for (int t=0;t<32;++t){
    if (tid < 192){
      float s = bh_;
      const float* wr = &w[tid*65];
#pragma unroll 8
      for (int g=0; g<64; ++g) s += wr[g]*hprev[g];
      gh[tid] = s;
    }
    __syncthreads();
    if (tid < 64){
      const float* gi = GI + ((size_t)(b*32 + t))*256;
      float r  = sigmoidf_(gi[tid]     + bih[tid]     + gh[tid]);
      float z  = sigmoidf_(gi[tid+64]  + bih[tid+64]  + gh[tid+64]);
      float n  = tanhf_(gi[tid+128] + bih[tid+128] + r*gh[tid+128]);
      float hn = (1.f - z)*n + z*hprev[tid];
      hprev[tid] = hn;
      OUTF[(size_t)b*2048 + t*64 + tid] = sigmoidf_(hn);
    }
    __syncthreads();
  }
}

// ---------------- heads: proj (sigmoid + L2-normalize) and y_pred ----------------
__global__ __launch_bounds__(256) void head_kernel(const float* __restrict__ OUTF, const float* __restrict__ linW,
                                                   const float* __restrict__ linb, const float* __restrict__ clsW,
                                                   const float* __restrict__ clsb, float* __restrict__ outp)
{
  const int b = blockIdx.x, tid = threadIdx.x;
  __shared__ float row[2048];
  __shared__ float pr[128];
  __shared__ float part[256];
  __shared__ float rn;
#pragma unroll
  for (int i=0;i<8;++i) row[tid + i*256] = OUTF[(size_t)b*2048 + tid + i*256];
  __syncthreads();
  {
    const int j = tid & 127, half = tid >> 7;
    const float* wr = linW + (size_t)j*2048 + half*1024;
    const float* xr = &row[half*1024];
    float s = 0;
    for (int k=0;k<1024;++k) s += xr[k]*wr[k];
    part[tid] = s;
  }
  __syncthreads();
  if (tid < 128){
    float v = part[tid] + part[tid+128] + linb[tid];
    v = sigmoidf_(v);
    pr[tid] = v;
    part[tid] = v*v;
  }
  __syncthreads();
  if (tid == 0){
    float ss = 0;
    for (int i2=0;i2<128;++i2) ss += part[i2];
    rn = 1.f/fmaxf(sqrtf(ss), 1e-12f);
  }
  __syncthreads();
  if (tid < 128) outp[(size_t)b*128 + tid] = pr[tid]*rn;
  if (tid < 192){
    const int c = tid >> 6, l = tid & 63;
    const float* wr = clsW + (size_t)c*2048;
    float s = 0;
    for (int k=l; k<2048; k+=64) s += row[k]*wr[k];
#pragma unroll
    for (int off=32; off; off>>=1) s += __shfl_down(s, off, 64);
    if (l == 0) outp[65536 + (size_t)b*3 + c] = sigmoidf_(s + clsb[c]);
  }
}

// ---------------- launch ----------------
extern "C" void kernel_launch(void* const* d_in, const int* in_sizes, int n_in,
                              void* d_out, int out_size, void* d_ws, size_t ws_size,
                              hipStream_t stream) {
  const float* x    = (const float*)d_in[0];
  const float* Aadj = (const float*)d_in[1];
  const float* chbW = (const float*)d_in[2];
  const float* bn1g = (const float*)d_in[3];
  const float* bn1b = (const float*)d_in[4];
  const float* bn2g = (const float*)d_in[5];
  const float* bn2b = (const float*)d_in[6];
  const float* Wq   = (const float*)d_in[7];
  const float* Wk   = (const float*)d_in[8];
  const float* Wv   = (const float*)d_in[9];
  const float* Wf   = (const float*)d_in[10];
  const float* bfv  = (const float*)d_in[11];
  const float* lng  = (const float*)d_in[12];
  const float* lnb  = (const float*)d_in[13];
  const float* Wih  = (const float*)d_in[14];
  const float* Whh  = (const float*)d_in[15];
  const float* bih  = (const float*)d_in[16];
  const float* bhh  = (const float*)d_in[17];
  const float* linW = (const float*)d_in[18];
  const float* linb = (const float*)d_in[19];
  const float* clsW = (const float*)d_in[20];
  const float* clsb = (const float*)d_in[21];

  char* ws = (char*)d_ws;
  u16*   Rb    = (u16*)(ws + OFF_A);
  u16*   OUTB  = (u16*)(ws + OFF_A);     // alias: attn out-proj result (R dead by then)
  u16*   YSEQ  = (u16*)(ws + OFF_B);
  u16*   QKV   = (u16*)(ws + OFF_C);
  u16*   CTX   = (u16*)(ws + OFF_D);
  u16*   HLN   = (u16*)(ws + OFF_D);     // alias: ctx dead after out-proj GEMM
  u16*   WqkvT = (u16*)(ws + OFF_E);
  u16*   WfT   = (u16*)(ws + OFF_WFT);
  u16*   WihT  = (u16*)(ws + OFF_WIH);
  float* Lhat  = (float*)(ws + OFF_LHAT);
  float* b1p   = (float*)(ws + OFF_B1P);
  float* b1s   = (float*)(ws + OFF_B1S);
  float* b2p   = (float*)(ws + OFF_B2P);
  float* b2s   = (float*)(ws + OFF_B2S);
  float* GI    = (float*)(ws + OFF_GI);   // alias: QKV dead after attention
  float* OUTF  = (float*)(ws + OFF_OUTF);

  wtrans_kernel<<<dim3(32,32,4), 256, 0, stream>>>(Wq, Wk, Wv, Wf, WqkvT, WfT);
  wih_kernel<<<dim3(256), 256, 0, stream>>>(Wih, WihT);
  bn1_part_kernel<<<dim3(32,64), 256, 0, stream>>>(x, b1p);
  bn1_fin_kernel<<<dim3(32), 256, 0, stream>>>(b1p, bn1g, bn1b, b1s);
  lap_kernel<<<dim3(32), 256, 0, stream>>>(Aadj, Lhat);
  cheby_kernel<<<dim3(16384), 256, 0, stream>>>(x, Lhat, chbW, b1s, Rb, b2p);
  bn2_fin_kernel<<<dim3(32), 256, 0, stream>>>(b2p, bn2g, bn2b, b2s);
  bn2apply_kernel<<<dim3(16384), 256, 0, stream>>>(Rb, b2s, YSEQ);
  gemm_bt_kernel<0><<<dim3(6144), 256, 0, stream>>>(YSEQ, WqkvT, (void*)QKV, 16384, 6144, 2048);
  attn_kernel<<<dim3(2048), 256, 0, stream>>>(QKV, CTX);
  gemm_bt_kernel<0><<<dim3(2048), 256, 0, stream>>>(CTX, WfT, (void*)OUTB, 16384, 2048, 2048);
  ln_kernel<<<dim3(16384), 256, 0, stream>>>(OUTB, YSEQ, bfv, lng, lnb, HLN);
  gemm_bt_kernel<1><<<dim3(256), 256, 0, stream>>>(HLN, WihT, (void*)GI, 16384, 256, 2048);
  gru_kernel<<<dim3(512), 256, 0, stream>>>(GI, Whh, bih, bhh, OUTF);
  head_kernel<<<dim3(512), 256, 0, stream>>>(OUTF, linW, linb, clsW, clsb, (float*)d_out);
}

// Round 2
// 1442.650 us; speedup vs baseline: 4.1914x; 4.1914x over previous
//
#include <hip/hip_runtime.h>
#include <hip/hip_bf16.h>

typedef unsigned short u16;
typedef __attribute__((ext_vector_type(8))) short short8;   // 8 x bf16 (4 VGPRs)
typedef __attribute__((ext_vector_type(4))) float f32x4;

// ---------------- helpers ----------------
__device__ __forceinline__ u16 f2bf(float f){
  union { float fv; unsigned int u; } v; v.fv = f;
  unsigned int u = v.u;
  u = u + 0x7FFFu + ((u >> 16) & 1u);   // RNE
  return (u16)(u >> 16);
}
__device__ __forceinline__ float bf2f(u16 h){
  union { unsigned int u; float fv; } v; v.u = ((unsigned int)h) << 16; return v.fv;
}
__device__ __forceinline__ float sigmoidf_(float x){ return 1.f/(1.f + __expf(-x)); }
__device__ __forceinline__ float tanhf_(float x){ return 2.f/(1.f + __expf(-2.f*x)) - 1.f; }

__device__ __forceinline__ void gload16(const void* g, void* l){
  __builtin_amdgcn_global_load_lds(
      (const __attribute__((address_space(1))) void*)g,
      (__attribute__((address_space(3))) void*)l, 16, 0, 0);
}
__device__ __forceinline__ f32x4 mfma_bf16(short8 a, short8 b, f32x4 c){
  return __builtin_amdgcn_mfma_f32_16x16x32_bf16(a, b, c, 0, 0, 0);
}

// ---------------- workspace layout (bytes) ----------------
constexpr size_t OFF_A    = 0;                       // R bf16 [32][512][64][32] ; later: attn-out bf16 [16384][2048]
constexpr size_t OFF_B    = 67108864;                // y_seq bf16 [16384][2048]
constexpr size_t OFF_C    = OFF_B + 67108864;        // QKV bf16 [16384][6144] ; later: GI f32 + OUTF f32
constexpr size_t OFF_D    = OFF_C + 201326592;       // ctx bf16 [16384][2048] ; later: h_ln bf16
constexpr size_t OFF_E    = OFF_D + 67108864;        // WqkvT bf16 [6144][2048]
constexpr size_t OFF_WFT  = OFF_E + 25165824;        // WfT bf16 [2048][2048]
constexpr size_t OFF_WIH  = OFF_WFT + 8388608;       // WihT bf16 [256][2048] (rows 192..255 zero)
constexpr size_t OFF_LHAT = OFF_WIH + 1048576;       // Lhat f32 [32][64][64]
constexpr size_t OFF_B1P  = OFF_LHAT + 524288;       // bn1 partials f32 [32][64][32][2]
constexpr size_t OFF_B1S  = OFF_B1P + 524288;        // bn1 scale/shift f32 [32][32][2]
constexpr size_t OFF_B2P  = OFF_B1S + 8192;          // bn2 partials f32 [32][512][32][2]
constexpr size_t OFF_B2S  = OFF_B2P + 4194304;       // bn2 scale/shift f32 [32][32][2]
constexpr size_t OFF_GI   = OFF_C;                   // f32 [16384][256]
constexpr size_t OFF_OUTF = OFF_C + 16777216;        // f32 [512][2048]

// ---------------- weight transpose: W[k][n] f32 -> WT[n][k] bf16 ----------------
__global__ __launch_bounds__(256) void wtrans_kernel(const float* __restrict__ Wq, const float* __restrict__ Wk,
                                                     const float* __restrict__ Wv, const float* __restrict__ Wf,
                                                     u16* __restrict__ WqkvT, u16* __restrict__ WfT)
{
  const int k0 = blockIdx.x*64, n0 = blockIdx.y*64, z = blockIdx.z;
  const float* src = (z==0)?Wq:(z==1)?Wk:(z==2)?Wv:Wf;
  u16* dst = (z<3) ? (WqkvT + (size_t)z*2048*2048) : WfT;
  __shared__ float tile[64][65];
  const int c = threadIdx.x & 63, r0 = threadIdx.x >> 6;
#pragma unroll
  for (int i=0;i<16;++i){ int r = r0 + i*4; tile[r][c] = src[(size_t)(k0+r)*2048 + n0 + c]; }
  __syncthreads();
#pragma unroll
  for (int i=0;i<16;++i){ int r = r0 + i*4; dst[(size_t)(n0+r)*2048 + k0 + c] = f2bf(tile[c][r]); }
}

__global__ __launch_bounds__(256) void wih_kernel(const float* __restrict__ Wih, u16* __restrict__ WT)
{
  const int row = blockIdx.x, tid = threadIdx.x;
#pragma unroll
  for (int i=0;i<8;++i){ int col = tid + i*256;
    float v = (row < 192) ? Wih[(size_t)row*2048 + col] : 0.f;
    WT[(size_t)row*2048 + col] = f2bf(v);
  }
}

// ---------------- BN1 stats (two-stage, deterministic) ----------------
__global__ __launch_bounds__(256) void bn1_part_kernel(const float* __restrict__ x, float* __restrict__ part)
{
  const int t = blockIdx.x, sl = blockIdx.y;
  const int f = threadIdx.x & 31, grp = threadIdx.x >> 5;
  float s = 0.f, ss = 0.f;
  for (int bb = 0; bb < 8; ++bb){
    const int b = sl*8 + bb;
    const float* xp = x + ((size_t)(b*32 + t))*2048;
    for (int i = 0; i < 8; ++i){
      int n = i*8 + grp;
      float v = xp[n*32 + f];
      s += v; ss += v*v;
    }
  }
  __shared__ float red[8][32][2];
  red[grp][f][0] = s; red[grp][f][1] = ss;
  __syncthreads();
  if (threadIdx.x < 32){
    float S=0, SS=0;
    for (int g=0; g<8; ++g){ S += red[g][threadIdx.x][0]; SS += red[g][threadIdx.x][1]; }
    size_t o = (((size_t)t*64 + sl)*32 + threadIdx.x)*2;
    part[o] = S; part[o+1] = SS;
  }
}

__global__ __launch_bounds__(256) void bn1_fin_kernel(const float* __restrict__ part, const float* __restrict__ g1,
                                                      const float* __restrict__ b1, float* __restrict__ out)
{
  const int t = blockIdx.x;
  const int f = threadIdx.x & 31, grp = threadIdx.x >> 5;
  float s=0, ss=0;
  for (int sl = grp; sl < 64; sl += 8){
    size_t o = (((size_t)t*64 + sl)*32 + f)*2;
    s += part[o]; ss += part[o+1];
  }
  __shared__ float red[8][32][2];
  red[grp][f][0]=s; red[grp][f][1]=ss;
  __syncthreads();
  if (threadIdx.x < 32){
    float S=0, SS=0;
    for (int g=0; g<8; ++g){ S+=red[g][threadIdx.x][0]; SS+=red[g][threadIdx.x][1]; }
    float mean = S*(1.f/32768.f);
    float var  = SS*(1.f/32768.f) - mean*mean;
    float sc   = g1[t*32+threadIdx.x]*rsqrtf(var + 1e-5f);
    out[(t*32+threadIdx.x)*2]   = sc;
    out[(t*32+threadIdx.x)*2+1] = b1[t*32+threadIdx.x] - mean*sc;
  }
}

// ---------------- per-t rescaled Laplacian ----------------
__global__ __launch_bounds__(256) void lap_kernel(const float* __restrict__ A, float* __restrict__ Lhat)
{
  const int t = blockIdx.x, tid = threadIdx.x;
  __shared__ float Ar[64][65];
  __shared__ float dr[64];
#pragma unroll
  for (int i=0;i<16;++i){ int idx = tid + i*256; int r = idx>>6, c = idx&63;
    float v = A[(size_t)t*4096 + idx]; v = fmaxf(v, 0.f); if (r==c) v = 0.f;
    Ar[r][c] = v; }
  __syncthreads();
  if (tid < 64){
    float s = 0;
    for (int c2=0;c2<64;++c2) s += Ar[tid][c2] + Ar[c2][tid];
    dr[tid] = rsqrtf(s + 1e-10f);
  }
  __syncthreads();
#pragma unroll
  for (int i=0;i<16;++i){ int idx = tid + i*256; int r = idx>>6, c = idx&63;
    Lhat[(size_t)t*4096 + idx] = -(Ar[r][c] + Ar[c][r]) * dr[r] * dr[c];
  }
}

// ---------------- Chebyshev conv: register-tiled rewrite ----------------
// Block: 256 threads = 4 waves, handles (t, 2 consecutive b).
// Wave w: b-slot s=w>>1, row-half h=w&1. Lane: nq=lane>>2 (rows n0,n0+1), fq=lane&3 (cols f0..f0+7).
// X ping-pong in LDS [slot][buf][64][36]; per-lane 2x8 register tile.
// #pragma unroll 1 on k-loops prevents the full-unroll VGPR spill seen in round 1 (VGPR=256, 9.5GB scratch).
__global__ __launch_bounds__(256) void cheby_kernel(const float* __restrict__ x, const float* __restrict__ Lhat,
                                                    const float* __restrict__ chebW, const float* __restrict__ bn1ss,
                                                    u16* __restrict__ Rb, float* __restrict__ bn2p)
{
  const int t = blockIdx.x >> 8, bp = blockIdx.x & 255, b0 = bp*2;
  const int tid = threadIdx.x;
  const int wave = tid >> 6, lane = tid & 63;
  const int s = wave >> 1, h = wave & 1;
  const int nq = lane >> 2, fq = lane & 3;
  const int n0 = h*32 + nq*2;
  const int f0 = fq*8;

  __shared__ float Ls[64][68];        // rows 272B (16B-aligned), bank (4n+m)%32
  __shared__ float Ws[4][32][36];     // rows 144B (16B-aligned)
  __shared__ float X[2][2][64][36];   // [slot][buf][row][col]
  __shared__ float red[2][2][32][2];
  __shared__ float scs[64];

  if (tid < 64) scs[tid] = bn1ss[t*64 + tid];
#pragma unroll
  for (int i=0;i<16;++i){ int idx = tid + i*256; Ls[idx>>6][idx&63] = Lhat[(size_t)t*4096 + idx]; }
#pragma unroll
  for (int i=0;i<16;++i){ int idx = tid + i*256; Ws[idx>>10][(idx>>5)&31][idx&31] = chebW[(size_t)t*4096 + idx]; }
  __syncthreads();

  // stage X0 = bn1(x) for both b-slots
#pragma unroll
  for (int ss=0; ss<2; ++ss){
    const float* xr = x + ((size_t)((b0+ss)*32 + t))*2048;
#pragma unroll
    for (int i=0;i<2;++i){
      int idx = tid + i*256;                 // float4 index 0..511
      int n = idx >> 3, f = (idx & 7)*4;
      f32x4 v = *(const f32x4*)&xr[idx*4];
      f32x4 w;
#pragma unroll
      for (int e=0;e<4;++e) w[e] = v[e]*scs[2*(f+e)] + scs[2*(f+e)+1];
      *(f32x4*)&X[ss][0][n][f] = w;
    }
  }
  __syncthreads();

  float racc[2][8];
#pragma unroll
  for (int e=0;e<8;++e){ racc[0][e]=0.f; racc[1][e]=0.f; }

#define RSTEP(K, SB) do { \
  _Pragma("unroll 1") \
  for (int ff=0; ff<32; ff+=4){ \
    f32x4 x0 = *(const f32x4*)&X[s][SB][n0][ff]; \
    f32x4 x1 = *(const f32x4*)&X[s][SB][n0+1][ff]; \
    _Pragma("unroll") \
    for (int q=0;q<4;++q){ \
      f32x4 w0 = *(const f32x4*)&Ws[K][ff+q][f0]; \
      f32x4 w1 = *(const f32x4*)&Ws[K][ff+q][f0+4]; \
      _Pragma("unroll") \
      for (int e=0;e<4;++e){ \
        racc[0][e]   += x0[q]*w0[e]; racc[0][4+e] += x0[q]*w1[e]; \
        racc[1][e]   += x1[q]*w0[e]; racc[1][4+e] += x1[q]*w1[e]; \
      } \
    } \
  } \
} while(0)

#define LSTEP(SB, DB, FIRST) do { \
  float xn0[8], xn1[8]; \
  _Pragma("unroll") for (int e=0;e<8;++e){ xn0[e]=0.f; xn1[e]=0.f; } \
  _Pragma("unroll 1") \
  for (int m=0;m<64;m+=4){ \
    f32x4 l0 = *(const f32x4*)&Ls[n0][m]; \
    f32x4 l1 = *(const f32x4*)&Ls[n0+1][m]; \
    _Pragma("unroll") \
    for (int q=0;q<4;++q){ \
      f32x4 xa = *(const f32x4*)&X[s][SB][m+q][f0]; \
      f32x4 xb = *(const f32x4*)&X[s][SB][m+q][f0+4]; \
      _Pragma("unroll") \
      for (int e=0;e<4;++e){ \
        xn0[e]   += l0[q]*xa[e]; xn0[4+e] += l0[q]*xb[e]; \
        xn1[e]   += l1[q]*xa[e]; xn1[4+e] += l1[q]*xb[e]; \
      } \
    } \
  } \
  f32x4 o00, o01, o10, o11; \
  if (FIRST){ \
    _Pragma("unroll") \
    for (int e=0;e<4;++e){ o00[e]=xn0[e]; o01[e]=xn0[4+e]; o10[e]=xn1[e]; o11[e]=xn1[4+e]; } \
  } else { \
    f32x4 d00 = *(const f32x4*)&X[s][DB][n0][f0]; \
    f32x4 d01 = *(const f32x4*)&X[s][DB][n0][f0+4]; \
    f32x4 d10 = *(const f32x4*)&X[s][DB][n0+1][f0]; \
    f32x4 d11 = *(const f32x4*)&X[s][DB][n0+1][f0+4]; \
    _Pragma("unroll") \
    for (int e=0;e<4;++e){ \
      o00[e]=2.f*xn0[e]  -d00[e]; o01[e]=2.f*xn0[4+e]-d01[e]; \
      o10[e]=2.f*xn1[e]  -d10[e]; o11[e]=2.f*xn1[4+e]-d11[e]; \
    } \
  } \
  *(f32x4*)&X[s][DB][n0][f0]     = o00; \
  *(f32x4*)&X[s][DB][n0][f0+4]   = o01; \
  *(f32x4*)&X[s][DB][n0+1][f0]   = o10; \
  *(f32x4*)&X[s][DB][n0+1][f0+4] = o11; \
} while(0)

  RSTEP(0, 0);
  LSTEP(0, 1, true);      // X1 = L X0
  __syncthreads();
  RSTEP(1, 1);
  LSTEP(1, 0, false);     // X2 = 2 L X1 - X0
  __syncthreads();
  RSTEP(2, 0);
  LSTEP(0, 1, false);     // X3 = 2 L X2 - X1
  __syncthreads();
  RSTEP(3, 1);

#undef RSTEP
#undef LSTEP

  // relu, Rb write (bf16), bn2 partials
  float se[8], sq[8];
  short8 v0, v1;
#pragma unroll
  for (int e=0;e<8;++e){
    float r0 = fmaxf(racc[0][e], 0.f), r1 = fmaxf(racc[1][e], 0.f);
    v0[e] = (short)f2bf(r0); v1[e] = (short)f2bf(r1);
    se[e] = r0 + r1; sq[e] = r0*r0 + r1*r1;
  }
  u16* rrow = Rb + ((size_t)(t*512 + b0 + s))*2048;
  *(short8*)&rrow[n0*32 + f0]     = v0;
  *(short8*)&rrow[(n0+1)*32 + f0] = v1;
#pragma unroll
  for (int e=0;e<8;++e){
#pragma unroll
    for (int msk=4; msk<64; msk<<=1){
      se[e] += __shfl_xor(se[e], msk, 64);
      sq[e] += __shfl_xor(sq[e], msk, 64);
    }
  }
  if (nq == 0){
#pragma unroll
    for (int e=0;e<8;++e){ red[s][h][f0+e][0] = se[e]; red[s][h][f0+e][1] = sq[e]; }
  }
  __syncthreads();
  if (tid < 128){
    int ss2 = tid>>6, r2 = tid&63, f = r2>>1, c = r2&1;
    bn2p[((size_t)(t*512 + b0 + ss2)*32 + f)*2 + c] = red[ss2][0][f][c] + red[ss2][1][f][c];
  }
}

__global__ __launch_bounds__(256) void bn2_fin_kernel(const float* __restrict__ part, const float* __restrict__ g2,
                                                      const float* __restrict__ b2, float* __restrict__ out)
{
  const int t = blockIdx.x;
  const int f = threadIdx.x & 31, grp = threadIdx.x >> 5;
  float s=0, ss=0;
  for (int b = grp; b < 512; b += 8){
    size_t o = ((size_t)(t*512+b)*32 + f)*2;
    s += part[o]; ss += part[o+1];
  }
  __shared__ float red[8][32][2];
  red[grp][f][0]=s; red[grp][f][1]=ss;
  __syncthreads();
  if (threadIdx.x < 32){
    float S=0, SS=0;
    for (int g=0; g<8; ++g){ S+=red[g][threadIdx.x][0]; SS+=red[g][threadIdx.x][1]; }
    float mean = S*(1.f/32768.f);
    float var  = SS*(1.f/32768.f) - mean*mean;
    float scv  = g2[t*32+threadIdx.x]*rsqrtf(var + 1e-5f);
    out[(t*32+threadIdx.x)*2]   = scv;
    out[(t*32+threadIdx.x)*2+1] = b2[t*32+threadIdx.x] - mean*scv;
  }
}

// ---------------- BN2 apply + sigmoid + torch stack/transpose/reshape permute ----------------
__global__ __launch_bounds__(256) void bn2apply_kernel(const u16* __restrict__ Rb, const float* __restrict__ ss,
                                                       u16* __restrict__ YS)
{
  const int t = blockIdx.x >> 9, b = blockIdx.x & 511, tid = threadIdx.x;
  __shared__ float scs[64];
  if (tid < 64) scs[tid] = ss[t*64 + tid];
  __syncthreads();
  const int n = tid >> 2, f0 = (tid & 3) << 3;
  short8 rv = *(const short8*)&Rb[((size_t)(t*512+b))*2048 + tid*8];
  short8 w;
#pragma unroll
  for (int e=0;e<8;++e){
    int f = f0 + e;
    float v = bf2f((u16)rv[e])*scs[f*2] + scs[f*2+1];
    w[e] = (short)f2bf(sigmoidf_(v));
  }
  *(short8*)&YS[((size_t)(b*32 + (n>>1)))*2048 + (n&1)*1024 + t*32 + f0] = w;
}

// ---------------- bf16 MFMA GEMM: C[M,N] = A[M,K] * BT[N,K]^T  (m97 structure) ----------------
template<int CB>   // 0 -> bf16 C, 1 -> f32 C
__global__ __launch_bounds__(256) void gemm_bt_kernel(const u16* __restrict__ A, const u16* __restrict__ BT,
                                                      void* __restrict__ C, int M, int N, int K)
{
  __shared__ u16 As[128*32];
  __shared__ u16 Bs[128*32];
  const int tid = threadIdx.x;
  const int wave = tid >> 6, lane = tid & 63;
  const int mblocks = M >> 7;
  const int mb = blockIdx.x % mblocks;
  const int nb = blockIdx.x / mblocks;
  const int lr = lane >> 2;
  const int lc = (lane & 3) << 3;
  const u16* Ag0 = A  + (size_t)(mb*128 + wave*16 + lr)*K + lc;
  const u16* Bg0 = BT + (size_t)(nb*128 + wave*16 + lr)*K + lc;
  const u16* Ag1 = Ag0 + (size_t)64*K;
  const u16* Bg1 = Bg0 + (size_t)64*K;
  u16* lA0 = &As[(wave*16)*32];
  u16* lA1 = &As[(wave*16+64)*32];
  u16* lB0 = &Bs[(wave*16)*32];
  u16* lB1 = &Bs[(wave*16+64)*32];
  const int wm = (wave >> 1)*64, wn = (wave & 1)*64;
  const int fr = lane & 15, fk = (lane >> 4) << 3;
  f32x4 acc[4][4] = {};
  for (int kt = 0; kt < K; kt += 32){
    __syncthreads();
    gload16(Ag0 + kt, lA0);
    gload16(Ag1 + kt, lA1);
    gload16(Bg0 + kt, lB0);
    gload16(Bg1 + kt, lB1);
    __syncthreads();
    short8 af[4], bfr[4];
#pragma unroll
    for (int i=0;i<4;++i) af[i]  = *(const short8*)&As[(wm + i*16 + fr)*32 + fk];
#pragma unroll
    for (int j=0;j<4;++j) bfr[j] = *(const short8*)&Bs[(wn + j*16 + fr)*32 + fk];
#pragma unroll
    for (int i=0;i<4;++i)
#pragma unroll
      for (int j=0;j<4;++j)
        acc[i][j] = mfma_bf16(af[i], bfr[j], acc[i][j]);
  }
  const int cr = (lane >> 4) << 2, cc = lane & 15;
#pragma unroll
  for (int i=0;i<4;++i)
#pragma unroll
    for (int j=0;j<4;++j)
#pragma unroll
      for (int r=0;r<4;++r){
        const size_t row = (size_t)(mb*128 + wm + i*16 + cr + r);
        const size_t col = (size_t)(nb*128 + wn + j*16 + cc);
        if (CB == 0) ((u16*)C)[row*(size_t)N + col] = f2bf(acc[i][j][r]);
        else        ((float*)C)[row*(size_t)N + col] = acc[i][j][r];
      }
}

// ---------------- attention: per (b,h) block, T=32, dh=512 ----------------
__global__ __launch_bounds__(256) void attn_kernel(const u16* __restrict__ QKV, u16* __restrict__ CTX)
{
  const int b = blockIdx.x >> 2, h = blockIdx.x & 3;
  const int tid = threadIdx.x;
  const int wave = tid >> 6, lane = tid & 63;
  __shared__ float spart[4][32][33];
  __shared__ float sm[32][33];
  __shared__ float rowinv[32];
  __shared__ u16 pb[32][40];
  __shared__ u16 vt[512][40];   // v^T : vt[d][t2]

  { // stage v^T
    const int t2 = tid >> 3;
    const size_t vbase = ((size_t)(b*32 + t2))*6144 + 4096 + h*512;
#pragma unroll
    for (int i = 0; i < 16; ++i){
      int d = (tid & 7)*64 + i*4;
      const u16* p = &QKV[vbase + d];
      vt[d+0][t2] = p[0]; vt[d+1][t2] = p[1]; vt[d+2][t2] = p[2]; vt[d+3][t2] = p[3];
    }
  }
  const int fr = lane & 15, fk = (lane >> 4) << 3;
  f32x4 sacc[2][2] = {};
  const size_t qrow = ((size_t)(b*32))*6144 + h*512;
#pragma unroll
  for (int kk = 0; kk < 4; ++kk){
    const int kof = wave*128 + kk*32 + fk;
    short8 qf0 = *(const short8*)&QKV[qrow + (size_t)fr*6144 + kof];
    short8 qf1 = *(const short8*)&QKV[qrow + (size_t)(fr+16)*6144 + kof];
    short8 kf0 = *(const short8*)&QKV[qrow + 2048 + (size_t)fr*6144 + kof];
    short8 kf1 = *(const short8*)&QKV[qrow + 2048 + (size_t)(fr+16)*6144 + kof];
    sacc[0][0] = mfma_bf16(qf0, kf0, sacc[0][0]);
    sacc[0][1] = mfma_bf16(qf0, kf1, sacc[0][1]);
    sacc[1][0] = mfma_bf16(qf1, kf0, sacc[1][0]);
    sacc[1][1] = mfma_bf16(qf1, kf1, sacc[1][1]);
  }
  const int cr = (lane >> 4) << 2, cc = lane & 15;
#pragma unroll
  for (int i=0;i<2;++i)
#pragma unroll
    for (int j=0;j<2;++j)
#pragma unroll
      for (int r=0;r<4;++r) spart[wave][i*16+cr+r][j*16+cc] = sacc[i][j][r];
  __syncthreads();
  const float scl = 0.04419417382415922f;  // 512^-0.5
  for (int e = tid; e < 1024; e += 256){
    int r = e >> 5, c = e & 31;
    sm[r][c] = (spart[0][r][c]+spart[1][r][c]+spart[2][r][c]+spart[3][r][c])*scl;
  }
  __syncthreads();
  if (tid < 32){
    float m = -1e30f;
    for (int c=0;c<32;++c) m = fmaxf(m, sm[tid][c]);
    float s = 0;
    for (int c=0;c<32;++c){ float e = __expf(sm[tid][c]-m); sm[tid][c] = e; s += e; }
    rowinv[tid] = 1.f/s;
  }
  __syncthreads();
  for (int e = tid; e < 1024; e += 256){
    int r = e>>5, c = e&31;
    pb[r][c] = f2bf(sm[r][c]*rowinv[r]);
  }
  __syncthreads();
  f32x4 cacc[2][8] = {};
  short8 pf0 = *(const short8*)&pb[fr][fk];
  short8 pf1 = *(const short8*)&pb[fr+16][fk];
#pragma unroll
  for (int j=0;j<8;++j){
    short8 vf = *(const short8*)&vt[wave*128 + j*16 + fr][fk];
    cacc[0][j] = mfma_bf16(pf0, vf, cacc[0][j]);
    cacc[1][j] = mfma_bf16(pf1, vf, cacc[1][j]);
  }
#pragma unroll
  for (int i=0;i<2;++i)
#pragma unroll
    for (int j=0;j<8;++j)
#pragma unroll
      for (int r=0;r<4;++r){
        int t1 = i*16 + cr + r;
        int d  = wave*128 + j*16 + cc;
        CTX[((size_t)(b*32+t1))*2048 + h*512 + d] = f2bf(cacc[i][j][r]);
      }
}

// ---------------- residual + bias + LayerNorm -> h_ln bf16 ----------------
__global__ __launch_bounds__(256) void ln_kernel(const u16* __restrict__ OUT, const u16* __restrict__ YS,
                                                 const float* __restrict__ bfv, const float* __restrict__ lng,
                                                 const float* __restrict__ lnb, u16* __restrict__ HLN)
{
  const int row = blockIdx.x, tid = threadIdx.x;
  const size_t base = (size_t)row*2048 + tid*8;
  short8 o8 = *(const short8*)&OUT[base];
  short8 y8 = *(const short8*)&YS[base];
  float hv[8]; float s = 0;
#pragma unroll
  for (int e=0;e<8;++e){ float v = bf2f((u16)o8[e]) + bf2f((u16)y8[e]) + bfv[tid*8+e]; hv[e]=v; s += v; }
  __shared__ float red[4];
#pragma unroll
  for (int off=32; off; off>>=1) s += __shfl_down(s, off, 64);
  if ((tid&63)==0) red[tid>>6] = s;
  __syncthreads();
  const float mu = (red[0]+red[1]+red[2]+red[3]) * (1.f/2048.f);
  float s2 = 0;
#pragma unroll
  for (int e=0;e<8;++e){ float d = hv[e]-mu; s2 += d*d; }
  __syncthreads();
#pragma unroll
  for (int off=32; off; off>>=1) s2 += __shfl_down(s2, off, 64);
  if ((tid&63)==0) red[tid>>6] = s2;
  __syncthreads();
  const float rstd = rsqrtf((red[0]+red[1]+red[2]+red[3])*(1.f/2048.f) + 1e-5f);
  short8 w;
#pragma unroll
  for (int e=0;e<8;++e) w[e] = (short)f2bf((hv[e]-mu)*rstd*lng[tid*8+e] + lnb[tid*8+e]);
  *(short8*)&HLN[base] = w;
}

// ---------------- GRU scan ----------------
__global__ __launch_bounds__(256) void gru_kernel(const float* __restrict__ GI, const float* __restrict__ Whh,
                                                  const float* __restrict__ bih, const float* __restrict__ bhh,
                                                  float* __restrict__ OUTF)
{
  const int b = blockIdx.x, tid = threadIdx.x;
  __shared__ float w[192*65];
  __shared__ float hprev[64];
  __shared__ float gh[192];
#pragma unroll
  for (int i=0;i<48;++i){ int idx = tid + i*256; w[(idx>>6)*65 + (idx&63)] = Whh[idx]; }
  if (tid < 64) hprev[tid] = 0.f;
  const float bh_ = (tid<192) ? bhh[tid] : 0.f;
  __syncthreads();
  for (int t=0;t<32;++t){
    if (tid < 192){
      float s = bh_;
      const float* wr = &w[tid*65];
#pragma unroll 8
      for (int g=0; g<64; ++g) s += wr[g]*hprev[g];
      gh[tid] = s;
    }
    __syncthreads();
    if (tid < 64){
      const float* gi = GI + ((size_t)(b*32 + t))*256;
      float r  = sigmoidf_(gi[tid]     + bih[tid]     + gh[tid]);
      float z  = sigmoidf_(gi[tid+64]  + bih[tid+64]  + gh[tid+64]);
      float n  = tanhf_(gi[tid+128] + bih[tid+128] + r*gh[tid+128]);
      float hn = (1.f - z)*n + z*hprev[tid];
      hprev[tid] = hn;
      OUTF[(size_t)b*2048 + t*64 + tid] = sigmoidf_(hn);
    }
    __syncthreads();
  }
}

// ---------------- heads ----------------
__global__ __launch_bounds__(256) void head_kernel(const float* __restrict__ OUTF, const float* __restrict__ linW,
                                                   const float* __restrict__ linb, const float* __restrict__ clsW,
                                                   const float* __restrict__ clsb, float* __restrict__ outp)
{
  const int b = blockIdx.x, tid = threadIdx.x;
  __shared__ float row[2048];
  __shared__ float pr[128];
  __shared__ float part[256];
  __shared__ float rn;
#pragma unroll
  for (int i=0;i<8;++i) row[tid + i*256] = OUTF[(size_t)b*2048 + tid + i*256];
  __syncthreads();
  {
    const int j = tid & 127, half = tid >> 7;
    const float* wr = linW + (size_t)j*2048 + half*1024;
    const float* xr = &row[half*1024];
    float s = 0;
    for (int k=0;k<1024;++k) s += xr[k]*wr[k];
    part[tid] = s;
  }
  __syncthreads();
  if (tid < 128){
    float v = part[tid] + part[tid+128] + linb[tid];
    v = sigmoidf_(v);
    pr[tid] = v;
    part[tid] = v*v;
  }
  __syncthreads();
  if (tid == 0){
    float ss = 0;
    for (int i2=0;i2<128;++i2) ss += part[i2];
    rn = 1.f/fmaxf(sqrtf(ss), 1e-12f);
  }
  __syncthreads();
  if (tid < 128) outp[(size_t)b*128 + tid] = pr[tid]*rn;
  if (tid < 192){
    const int c = tid >> 6, l = tid & 63;
    const float* wr = clsW + (size_t)c*2048;
    float s = 0;
    for (int k=l; k<2048; k+=64) s += row[k]*wr[k];
#pragma unroll
    for (int off=32; off; off>>=1) s += __shfl_down(s, off, 64);
    if (l == 0) outp[65536 + (size_t)b*3 + c] = sigmoidf_(s + clsb[c]);
  }
}

// ---------------- launch ----------------
extern "C" void kernel_launch(void* const* d_in, const int* in_sizes, int n_in,
                              void* d_out, int out_size, void* d_ws, size_t ws_size,
                              hipStream_t stream) {
  const float* x    = (const float*)d_in[0];
  const float* Aadj = (const float*)d_in[1];
  const float* chbW = (const float*)d_in[2];
  const float* bn1g = (const float*)d_in[3];
  const float* bn1b = (const float*)d_in[4];
  const float* bn2g = (const float*)d_in[5];
  const float* bn2b = (const float*)d_in[6];
  const float* Wq   = (const float*)d_in[7];
  const float* Wk   = (const float*)d_in[8];
  const float* Wv   = (const float*)d_in[9];
  const float* Wf   = (const float*)d_in[10];
  const float* bfv  = (const float*)d_in[11];
  const float* lng  = (const float*)d_in[12];
  const float* lnb  = (const float*)d_in[13];
  const float* Wih  = (const float*)d_in[14];
  const float* Whh  = (const float*)d_in[15];
  const float* bih  = (const float*)d_in[16];
  const float* bhh  = (const float*)d_in[17];
  const float* linW = (const float*)d_in[18];
  const float* linb = (const float*)d_in[19];
  const float* clsW = (const float*)d_in[20];
  const float* clsb = (const float*)d_in[21];

  char* ws = (char*)d_ws;
  u16*   Rb    = (u16*)(ws + OFF_A);
  u16*   OUTB  = (u16*)(ws + OFF_A);
  u16*   YSEQ  = (u16*)(ws + OFF_B);
  u16*   QKV   = (u16*)(ws + OFF_C);
  u16*   CTX   = (u16*)(ws + OFF_D);
  u16*   HLN   = (u16*)(ws + OFF_D);
  u16*   WqkvT = (u16*)(ws + OFF_E);
  u16*   WfT   = (u16*)(ws + OFF_WFT);
  u16*   WihT  = (u16*)(ws + OFF_WIH);
  float* Lhat  = (float*)(ws + OFF_LHAT);
  float* b1p   = (float*)(ws + OFF_B1P);
  float* b1s   = (float*)(ws + OFF_B1S);
  float* b2p   = (float*)(ws + OFF_B2P);
  float* b2s   = (float*)(ws + OFF_B2S);
  float* GI    = (float*)(ws + OFF_GI);
  float* OUTF  = (float*)(ws + OFF_OUTF);

  wtrans_kernel<<<dim3(32,32,4), 256, 0, stream>>>(Wq, Wk, Wv, Wf, WqkvT, WfT);
  wih_kernel<<<dim3(256), 256, 0, stream>>>(Wih, WihT);
  bn1_part_kernel<<<dim3(32,64), 256, 0, stream>>>(x, b1p);
  bn1_fin_kernel<<<dim3(32), 256, 0, stream>>>(b1p, bn1g, bn1b, b1s);
  lap_kernel<<<dim3(32), 256, 0, stream>>>(Aadj, Lhat);
  cheby_kernel<<<dim3(8192), 256, 0, stream>>>(x, Lhat, chbW, b1s, Rb, b2p);
  bn2_fin_kernel<<<dim3(32), 256, 0, stream>>>(b2p, bn2g, bn2b, b2s);
  bn2apply_kernel<<<dim3(16384), 256, 0, stream>>>(Rb, b2s, YSEQ);
  gemm_bt_kernel<0><<<dim3(6144), 256, 0, stream>>>(YSEQ, WqkvT, (void*)QKV, 16384, 6144, 2048);
  attn_kernel<<<dim3(2048), 256, 0, stream>>>(QKV, CTX);
  gemm_bt_kernel<0><<<dim3(2048), 256, 0, stream>>>(CTX, WfT, (void*)OUTB, 16384, 2048, 2048);
  ln_kernel<<<dim3(16384), 256, 0, stream>>>(OUTB, YSEQ, bfv, lng, lnb, HLN);
  gemm_bt_kernel<1><<<dim3(256), 256, 0, stream>>>(HLN, WihT, (void*)GI, 16384, 256, 2048);
  gru_kernel<<<dim3(512), 256, 0, stream>>>(GI, Whh, bih, bhh, OUTF);
  head_kernel<<<dim3(512), 256, 0, stream>>>(OUTF, linW, linb, clsW, clsb, (float*)d_out);
}

// Round 3
// 1213.993 us; speedup vs baseline: 4.9808x; 1.1884x over previous
//
#include <hip/hip_runtime.h>
#include <hip/hip_bf16.h>

typedef unsigned short u16;
typedef __attribute__((ext_vector_type(8))) short short8;   // 8 x bf16 (4 VGPRs)
typedef __attribute__((ext_vector_type(4))) float f32x4;

// ---------------- helpers ----------------
__device__ __forceinline__ u16 f2bf(float f){
  union { float fv; unsigned int u; } v; v.fv = f;
  unsigned int u = v.u;
  u = u + 0x7FFFu + ((u >> 16) & 1u);   // RNE
  return (u16)(u >> 16);
}
__device__ __forceinline__ float bf2f(u16 h){
  union { unsigned int u; float fv; } v; v.u = ((unsigned int)h) << 16; return v.fv;
}
__device__ __forceinline__ float sigmoidf_(float x){ return 1.f/(1.f + __expf(-x)); }
__device__ __forceinline__ float tanhf_(float x){ return 2.f/(1.f + __expf(-2.f*x)) - 1.f; }

__device__ __forceinline__ void gload16(const void* g, void* l){
  __builtin_amdgcn_global_load_lds(
      (const __attribute__((address_space(1))) void*)g,
      (__attribute__((address_space(3))) void*)l, 16, 0, 0);
}
__device__ __forceinline__ f32x4 mfma_bf16(short8 a, short8 b, f32x4 c){
  return __builtin_amdgcn_mfma_f32_16x16x32_bf16(a, b, c, 0, 0, 0);
}

#define ASM_VMCNT2 asm volatile("s_waitcnt vmcnt(2)" ::: "memory")
#define ASM_VMCNT0 asm volatile("s_waitcnt vmcnt(0)" ::: "memory")
#define ASM_LGK0   asm volatile("s_waitcnt lgkmcnt(0)" ::: "memory")
#define SCHB       __builtin_amdgcn_sched_barrier(0)
#define SBAR       do { asm volatile("" ::: "memory"); __builtin_amdgcn_s_barrier(); asm volatile("" ::: "memory"); } while(0)

// ---------------- workspace layout (bytes) ----------------
constexpr size_t OFF_A    = 0;                       // R bf16 [32][512][64][32] ; later: attn-out bf16 [16384][2048]
constexpr size_t OFF_B    = 67108864;                // y_seq bf16 [16384][2048]
constexpr size_t OFF_C    = OFF_B + 67108864;        // QKV bf16 [16384][6144] ; later: GI f32 + OUTF f32
constexpr size_t OFF_D    = OFF_C + 201326592;       // ctx bf16 [16384][2048] ; later: h_ln bf16
constexpr size_t OFF_E    = OFF_D + 67108864;        // WqkvT bf16 [6144][2048]
constexpr size_t OFF_WFT  = OFF_E + 25165824;        // WfT bf16 [2048][2048]
constexpr size_t OFF_WIH  = OFF_WFT + 8388608;       // WihT bf16 [256][2048] (rows 192..255 zero)
constexpr size_t OFF_LHAT = OFF_WIH + 1048576;       // Lhat f32 [32][64][64]
constexpr size_t OFF_B1P  = OFF_LHAT + 524288;       // bn1 partials f32 [32][64][32][2]
constexpr size_t OFF_B1S  = OFF_B1P + 524288;        // bn1 scale/shift f32 [32][32][2]
constexpr size_t OFF_B2P  = OFF_B1S + 8192;          // bn2 partials f32 [32][512][32][2]
constexpr size_t OFF_B2S  = OFF_B2P + 4194304;       // bn2 scale/shift f32 [32][32][2]
constexpr size_t OFF_GI   = OFF_C;                   // f32 [16384][256]
constexpr size_t OFF_OUTF = OFF_C + 16777216;        // f32 [512][2048]

// ---------------- weight transpose: W[k][n] f32 -> WT[n][k] bf16 ----------------
__global__ __launch_bounds__(256) void wtrans_kernel(const float* __restrict__ Wq, const float* __restrict__ Wk,
                                                     const float* __restrict__ Wv, const float* __restrict__ Wf,
                                                     u16* __restrict__ WqkvT, u16* __restrict__ WfT)
{
  const int k0 = blockIdx.x*64, n0 = blockIdx.y*64, z = blockIdx.z;
  const float* src = (z==0)?Wq:(z==1)?Wk:(z==2)?Wv:Wf;
  u16* dst = (z<3) ? (WqkvT + (size_t)z*2048*2048) : WfT;
  __shared__ float tile[64][65];
  const int c = threadIdx.x & 63, r0 = threadIdx.x >> 6;
#pragma unroll
  for (int i=0;i<16;++i){ int r = r0 + i*4; tile[r][c] = src[(size_t)(k0+r)*2048 + n0 + c]; }
  __syncthreads();
#pragma unroll
  for (int i=0;i<16;++i){ int r = r0 + i*4; dst[(size_t)(n0+r)*2048 + k0 + c] = f2bf(tile[c][r]); }
}

__global__ __launch_bounds__(256) void wih_kernel(const float* __restrict__ Wih, u16* __restrict__ WT)
{
  const int row = blockIdx.x, tid = threadIdx.x;
#pragma unroll
  for (int i=0;i<8;++i){ int col = tid + i*256;
    float v = (row < 192) ? Wih[(size_t)row*2048 + col] : 0.f;
    WT[(size_t)row*2048 + col] = f2bf(v);
  }
}

// ---------------- BN1 stats (two-stage, deterministic) ----------------
__global__ __launch_bounds__(256) void bn1_part_kernel(const float* __restrict__ x, float* __restrict__ part)
{
  const int t = blockIdx.x, sl = blockIdx.y;
  const int f = threadIdx.x & 31, grp = threadIdx.x >> 5;
  float s = 0.f, ss = 0.f;
  for (int bb = 0; bb < 8; ++bb){
    const int b = sl*8 + bb;
    const float* xp = x + ((size_t)(b*32 + t))*2048;
    for (int i = 0; i < 8; ++i){
      int n = i*8 + grp;
      float v = xp[n*32 + f];
      s += v; ss += v*v;
    }
  }
  __shared__ float red[8][32][2];
  red[grp][f][0] = s; red[grp][f][1] = ss;
  __syncthreads();
  if (threadIdx.x < 32){
    float S=0, SS=0;
    for (int g=0; g<8; ++g){ S += red[g][threadIdx.x][0]; SS += red[g][threadIdx.x][1]; }
    size_t o = (((size_t)t*64 + sl)*32 + threadIdx.x)*2;
    part[o] = S; part[o+1] = SS;
  }
}

__global__ __launch_bounds__(256) void bn1_fin_kernel(const float* __restrict__ part, const float* __restrict__ g1,
                                                      const float* __restrict__ b1, float* __restrict__ out)
{
  const int t = blockIdx.x;
  const int f = threadIdx.x & 31, grp = threadIdx.x >> 5;
  float s=0, ss=0;
  for (int sl = grp; sl < 64; sl += 8){
    size_t o = (((size_t)t*64 + sl)*32 + f)*2;
    s += part[o]; ss += part[o+1];
  }
  __shared__ float red[8][32][2];
  red[grp][f][0]=s; red[grp][f][1]=ss;
  __syncthreads();
  if (threadIdx.x < 32){
    float S=0, SS=0;
    for (int g=0; g<8; ++g){ S+=red[g][threadIdx.x][0]; SS+=red[g][threadIdx.x][1]; }
    float mean = S*(1.f/32768.f);
    float var  = SS*(1.f/32768.f) - mean*mean;
    float sc   = g1[t*32+threadIdx.x]*rsqrtf(var + 1e-5f);
    out[(t*32+threadIdx.x)*2]   = sc;
    out[(t*32+threadIdx.x)*2+1] = b1[t*32+threadIdx.x] - mean*sc;
  }
}

// ---------------- per-t rescaled Laplacian ----------------
__global__ __launch_bounds__(256) void lap_kernel(const float* __restrict__ A, float* __restrict__ Lhat)
{
  const int t = blockIdx.x, tid = threadIdx.x;
  __shared__ float Ar[64][65];
  __shared__ float dr[64];
#pragma unroll
  for (int i=0;i<16;++i){ int idx = tid + i*256; int r = idx>>6, c = idx&63;
    float v = A[(size_t)t*4096 + idx]; v = fmaxf(v, 0.f); if (r==c) v = 0.f;
    Ar[r][c] = v; }
  __syncthreads();
  if (tid < 64){
    float s = 0;
    for (int c2=0;c2<64;++c2) s += Ar[tid][c2] + Ar[c2][tid];
    dr[tid] = rsqrtf(s + 1e-10f);
  }
  __syncthreads();
#pragma unroll
  for (int i=0;i<16;++i){ int idx = tid + i*256; int r = idx>>6, c = idx&63;
    Lhat[(size_t)t*4096 + idx] = -(Ar[r][c] + Ar[c][r]) * dr[r] * dr[c];
  }
}

// ---------------- Chebyshev conv: register-tiled ----------------
__global__ __launch_bounds__(256) void cheby_kernel(const float* __restrict__ x, const float* __restrict__ Lhat,
                                                    const float* __restrict__ chebW, const float* __restrict__ bn1ss,
                                                    u16* __restrict__ Rb, float* __restrict__ bn2p)
{
  const int t = blockIdx.x >> 8, bp = blockIdx.x & 255, b0 = bp*2;
  const int tid = threadIdx.x;
  const int wave = tid >> 6, lane = tid & 63;
  const int s = wave >> 1, h = wave & 1;
  const int nq = lane >> 2, fq = lane & 3;
  const int n0 = h*32 + nq*2;
  const int f0 = fq*8;

  __shared__ float Ls[64][68];
  __shared__ float Ws[4][32][36];
  __shared__ float X[2][2][64][36];
  __shared__ float red[2][2][32][2];
  __shared__ float scs[64];

  if (tid < 64) scs[tid] = bn1ss[t*64 + tid];
#pragma unroll
  for (int i=0;i<16;++i){ int idx = tid + i*256; Ls[idx>>6][idx&63] = Lhat[(size_t)t*4096 + idx]; }
#pragma unroll
  for (int i=0;i<16;++i){ int idx = tid + i*256; Ws[idx>>10][(idx>>5)&31][idx&31] = chebW[(size_t)t*4096 + idx]; }
  __syncthreads();

#pragma unroll
  for (int ss=0; ss<2; ++ss){
    const float* xr = x + ((size_t)((b0+ss)*32 + t))*2048;
#pragma unroll
    for (int i=0;i<2;++i){
      int idx = tid + i*256;
      int n = idx >> 3, f = (idx & 7)*4;
      f32x4 v = *(const f32x4*)&xr[idx*4];
      f32x4 w;
#pragma unroll
      for (int e=0;e<4;++e) w[e] = v[e]*scs[2*(f+e)] + scs[2*(f+e)+1];
      *(f32x4*)&X[ss][0][n][f] = w;
    }
  }
  __syncthreads();

  float racc[2][8];
#pragma unroll
  for (int e=0;e<8;++e){ racc[0][e]=0.f; racc[1][e]=0.f; }

#define RSTEP(K, SB) do { \
  _Pragma("unroll 1") \
  for (int ff=0; ff<32; ff+=4){ \
    f32x4 x0 = *(const f32x4*)&X[s][SB][n0][ff]; \
    f32x4 x1 = *(const f32x4*)&X[s][SB][n0+1][ff]; \
    _Pragma("unroll") \
    for (int q=0;q<4;++q){ \
      f32x4 w0 = *(const f32x4*)&Ws[K][ff+q][f0]; \
      f32x4 w1 = *(const f32x4*)&Ws[K][ff+q][f0+4]; \
      _Pragma("unroll") \
      for (int e=0;e<4;++e){ \
        racc[0][e]   += x0[q]*w0[e]; racc[0][4+e] += x0[q]*w1[e]; \
        racc[1][e]   += x1[q]*w0[e]; racc[1][4+e] += x1[q]*w1[e]; \
      } \
    } \
  } \
} while(0)

#define LSTEP(SB, DB, FIRST) do { \
  float xn0[8], xn1[8]; \
  _Pragma("unroll") for (int e=0;e<8;++e){ xn0[e]=0.f; xn1[e]=0.f; } \
  _Pragma("unroll 1") \
  for (int m=0;m<64;m+=4){ \
    f32x4 l0 = *(const f32x4*)&Ls[n0][m]; \
    f32x4 l1 = *(const f32x4*)&Ls[n0+1][m]; \
    _Pragma("unroll") \
    for (int q=0;q<4;++q){ \
      f32x4 xa = *(const f32x4*)&X[s][SB][m+q][f0]; \
      f32x4 xb = *(const f32x4*)&X[s][SB][m+q][f0+4]; \
      _Pragma("unroll") \
      for (int e=0;e<4;++e){ \
        xn0[e]   += l0[q]*xa[e]; xn0[4+e] += l0[q]*xb[e]; \
        xn1[e]   += l1[q]*xa[e]; xn1[4+e] += l1[q]*xb[e]; \
      } \
    } \
  } \
  f32x4 o00, o01, o10, o11; \
  if (FIRST){ \
    _Pragma("unroll") \
    for (int e=0;e<4;++e){ o00[e]=xn0[e]; o01[e]=xn0[4+e]; o10[e]=xn1[e]; o11[e]=xn1[4+e]; } \
  } else { \
    f32x4 d00 = *(const f32x4*)&X[s][DB][n0][f0]; \
    f32x4 d01 = *(const f32x4*)&X[s][DB][n0][f0+4]; \
    f32x4 d10 = *(const f32x4*)&X[s][DB][n0+1][f0]; \
    f32x4 d11 = *(const f32x4*)&X[s][DB][n0+1][f0+4]; \
    _Pragma("unroll") \
    for (int e=0;e<4;++e){ \
      o00[e]=2.f*xn0[e]  -d00[e]; o01[e]=2.f*xn0[4+e]-d01[e]; \
      o10[e]=2.f*xn1[e]  -d10[e]; o11[e]=2.f*xn1[4+e]-d11[e]; \
    } \
  } \
  *(f32x4*)&X[s][DB][n0][f0]     = o00; \
  *(f32x4*)&X[s][DB][n0][f0+4]   = o01; \
  *(f32x4*)&X[s][DB][n0+1][f0]   = o10; \
  *(f32x4*)&X[s][DB][n0+1][f0+4] = o11; \
} while(0)

  RSTEP(0, 0);
  LSTEP(0, 1, true);
  __syncthreads();
  RSTEP(1, 1);
  LSTEP(1, 0, false);
  __syncthreads();
  RSTEP(2, 0);
  LSTEP(0, 1, false);
  __syncthreads();
  RSTEP(3, 1);

#undef RSTEP
#undef LSTEP

  float se[8], sq[8];
  short8 v0, v1;
#pragma unroll
  for (int e=0;e<8;++e){
    float r0 = fmaxf(racc[0][e], 0.f), r1 = fmaxf(racc[1][e], 0.f);
    v0[e] = (short)f2bf(r0); v1[e] = (short)f2bf(r1);
    se[e] = r0 + r1; sq[e] = r0*r0 + r1*r1;
  }
  u16* rrow = Rb + ((size_t)(t*512 + b0 + s))*2048;
  *(short8*)&rrow[n0*32 + f0]     = v0;
  *(short8*)&rrow[(n0+1)*32 + f0] = v1;
#pragma unroll
  for (int e=0;e<8;++e){
#pragma unroll
    for (int msk=4; msk<64; msk<<=1){
      se[e] += __shfl_xor(se[e], msk, 64);
      sq[e] += __shfl_xor(sq[e], msk, 64);
    }
  }
  if (nq == 0){
#pragma unroll
    for (int e=0;e<8;++e){ red[s][h][f0+e][0] = se[e]; red[s][h][f0+e][1] = sq[e]; }
  }
  __syncthreads();
  if (tid < 128){
    int ss2 = tid>>6, r2 = tid&63, f = r2>>1, c = r2&1;
    bn2p[((size_t)(t*512 + b0 + ss2)*32 + f)*2 + c] = red[ss2][0][f][c] + red[ss2][1][f][c];
  }
}

__global__ __launch_bounds__(256) void bn2_fin_kernel(const float* __restrict__ part, const float* __restrict__ g2,
                                                      const float* __restrict__ b2, float* __restrict__ out)
{
  const int t = blockIdx.x;
  const int f = threadIdx.x & 31, grp = threadIdx.x >> 5;
  float s=0, ss=0;
  for (int b = grp; b < 512; b += 8){
    size_t o = ((size_t)(t*512+b)*32 + f)*2;
    s += part[o]; ss += part[o+1];
  }
  __shared__ float red[8][32][2];
  red[grp][f][0]=s; red[grp][f][1]=ss;
  __syncthreads();
  if (threadIdx.x < 32){
    float S=0, SS=0;
    for (int g=0; g<8; ++g){ S+=red[g][threadIdx.x][0]; SS+=red[g][threadIdx.x][1]; }
    float mean = S*(1.f/32768.f);
    float var  = SS*(1.f/32768.f) - mean*mean;
    float scv  = g2[t*32+threadIdx.x]*rsqrtf(var + 1e-5f);
    out[(t*32+threadIdx.x)*2]   = scv;
    out[(t*32+threadIdx.x)*2+1] = b2[t*32+threadIdx.x] - mean*scv;
  }
}

// ---------------- BN2 apply + sigmoid + permute ----------------
__global__ __launch_bounds__(256) void bn2apply_kernel(const u16* __restrict__ Rb, const float* __restrict__ ss,
                                                       u16* __restrict__ YS)
{
  const int t = blockIdx.x >> 9, b = blockIdx.x & 511, tid = threadIdx.x;
  __shared__ float scs[64];
  if (tid < 64) scs[tid] = ss[t*64 + tid];
  __syncthreads();
  const int n = tid >> 2, f0 = (tid & 3) << 3;
  short8 rv = *(const short8*)&Rb[((size_t)(t*512+b))*2048 + tid*8];
  short8 w;
#pragma unroll
  for (int e=0;e<8;++e){
    int f = f0 + e;
    float v = bf2f((u16)rv[e])*scs[f*2] + scs[f*2+1];
    w[e] = (short)f2bf(sigmoidf_(v));
  }
  *(short8*)&YS[((size_t)(b*32 + (n>>1)))*2048 + (n&1)*1024 + t*32 + f0] = w;
}

// ============ 256x256 8-phase bf16 MFMA GEMM (T1+T2+T3+T4+T5) ============
// C[M,N] = A[M,K] * BT[N,K]^T.  512 thr = 8 waves (2M x 4N), BK=64, LDS 128KB 2-buf.
// LDS halves: A: buf*32768 + h*8192 ; B: buf*32768 + 16384 + h*8192 (u16 units).
// Swizzle: element col ^= (row&7)<<3 (16B slots), applied on pre-swizzled global
// source (linear global_load_lds dest) and on ds_read addresses (rule #21).
// Schedule per iteration i (tiles 2i->buf0 ph0-3, 2i+1->buf1 ph4-7):
//   ph0: dsA(buf0,m0-3)+dsB(buf0,n0-1) | stage t+1 A1 | bar lgk0 MMA(0,0) bar
//   ph1: dsB(buf0,n2-3)                | stage t+1 B0 | bar lgk0 MMA(0,1) bar
//   ph2: dsA(buf0,m4-7)                | stage t+1 B1 | bar lgk0 MMA(1,0) bar
//   ph3:                                 stage t+2 A0 | vmcnt(2) bar MMA(1,1) bar
//   ph4-7: mirror on buf1, stages t+2 A1,B0,B1 and t+3 A0, vmcnt(2) at ph7.
// Reads of a region always complete one phase before the overwriting stage issues.
template<int CB>   // 0 -> bf16 C, 1 -> f32 C
__global__ __launch_bounds__(512, 2) void gemm256_kernel(const u16* __restrict__ A, const u16* __restrict__ BT,
                                                         void* __restrict__ C, int M, int N, int K)
{
  __shared__ u16 smem[65536];   // 128 KiB
  const int tid = threadIdx.x, wid = tid >> 6, lane = tid & 63;
  const int nwg = gridDim.x, cpx = nwg >> 3;
  const int logical = ((int)blockIdx.x & 7)*cpx + ((int)blockIdx.x >> 3);  // XCD swizzle (nwg%8==0)
  const int MB = M >> 8;
  const int mb = logical % MB, nb = logical / MB;
  const int m0 = mb << 8, n0g = nb << 8;
  const int nkt = K >> 6;
  const int nit = nkt >> 1;

  const int wr = wid >> 2, wc = wid & 3;
  const int fr = lane & 15, fk = (lane >> 4) << 3;
  const int cz0 = fk ^ ((fr & 7) << 3);          // swizzled k-offsets (u16 units)
  const int cz1 = (32 + fk) ^ ((fr & 7) << 3);
  const int srow = wid*16 + (lane >> 3);          // staging row within 128-half
  const int scol = ((lane & 7) ^ (lane >> 3)) << 3;  // pre-swizzled global k-offset
  const int bhalf = wc >> 1, brow0 = (wc & 1) << 6;

  f32x4 acc[8][4] = {};
  short8 af[4][2], bg[4][2];

#define STG(PTR, R0, DSTB, TK, H) do { if ((TK) < nkt) { \
  const u16* _g = (PTR) + (size_t)((R0) + ((H)<<7) + srow)*(size_t)K + (size_t)(((TK)<<6) + scol); \
  u16* _d = &smem[(DSTB) + ((H)<<13) + (wid<<10)]; \
  gload16(_g, _d); gload16(_g + ((size_t)K<<3), _d + 512); } } while(0)

#define DSA(BUF, QM) { _Pragma("unroll") for(int m2=0;m2<4;++m2){ \
  const u16* _p = &smem[(BUF) + wr*8192 + (((QM)*64 + m2*16 + fr)<<6)]; \
  af[m2][0] = *(const short8*)(_p + cz0); af[m2][1] = *(const short8*)(_p + cz1); } }

#define DSB(BUF, QN) { _Pragma("unroll") for(int n2=0;n2<2;++n2){ \
  const u16* _p = &smem[(BUF) + 16384 + bhalf*8192 + ((brow0 + (QN)*32 + n2*16 + fr)<<6)]; \
  bg[(QN)*2+n2][0] = *(const short8*)(_p + cz0); bg[(QN)*2+n2][1] = *(const short8*)(_p + cz1); } }

#define MMA(QM, QN) { __builtin_amdgcn_s_setprio(1); \
  _Pragma("unroll") for(int m2=0;m2<4;++m2) _Pragma("unroll") for(int n2=0;n2<2;++n2) { \
    acc[(QM)*4+m2][(QN)*2+n2] = mfma_bf16(af[m2][0], bg[(QN)*2+n2][0], acc[(QM)*4+m2][(QN)*2+n2]); \
    acc[(QM)*4+m2][(QN)*2+n2] = mfma_bf16(af[m2][1], bg[(QN)*2+n2][1], acc[(QM)*4+m2][(QN)*2+n2]); } \
  __builtin_amdgcn_s_setprio(0); }

  // prologue: tile0 -> buf0 (4 halves), tile1 A0 -> buf1
  STG(A,  m0,  0,     0, 0); STG(A,  m0,  0,     0, 1);
  STG(BT, n0g, 16384, 0, 0); STG(BT, n0g, 16384, 0, 1);
  STG(A,  m0,  32768, 1, 0);
  ASM_VMCNT2; SBAR;

  for (int i = 0; i < nit; ++i){
    const int kb = i*2;
    // ph0
    DSA(0, 0); DSB(0, 0);
    STG(A, m0, 32768, kb+1, 1);
    SBAR; ASM_LGK0; SCHB; MMA(0,0); SBAR;
    // ph1
    DSB(0, 1);
    STG(BT, n0g, 49152, kb+1, 0);
    SBAR; ASM_LGK0; SCHB; MMA(0,1); SBAR;
    // ph2
    DSA(0, 1);
    STG(BT, n0g, 49152, kb+1, 1);
    SBAR; ASM_LGK0; SCHB; MMA(1,0); SBAR;
    // ph3
    STG(A, m0, 0, kb+2, 0);
    if (kb + 2 >= nkt) { ASM_VMCNT0; } else { ASM_VMCNT2; }
    SBAR; MMA(1,1); SBAR;
    // ph4
    DSA(32768, 0); DSB(32768, 0);
    STG(A, m0, 0, kb+2, 1);
    SBAR; ASM_LGK0; SCHB; MMA(0,0); SBAR;
    // ph5
    DSB(32768, 1);
    STG(BT, n0g, 16384, kb+2, 0);
    SBAR; ASM_LGK0; SCHB; MMA(0,1); SBAR;
    // ph6
    DSA(32768, 1);
    STG(BT, n0g, 16384, kb+2, 1);
    SBAR; ASM_LGK0; SCHB; MMA(1,0); SBAR;
    // ph7
    STG(A, m0, 32768, kb+3, 0);
    ASM_VMCNT2;
    SBAR; MMA(1,1); SBAR;
  }

#undef STG
#undef DSA
#undef DSB
#undef MMA

  // epilogue C-write
  const int cr = (lane >> 4) << 2, cc = lane & 15;
#pragma unroll
  for (int mf=0; mf<8; ++mf)
#pragma unroll
    for (int nf=0; nf<4; ++nf)
#pragma unroll
      for (int r=0; r<4; ++r){
        const size_t row = (size_t)(m0 + wr*128 + mf*16 + cr + r);
        const size_t col = (size_t)(n0g + wc*64 + nf*16 + cc);
        if (CB == 0) ((u16*)C)[row*(size_t)N + col] = f2bf(acc[mf][nf][r]);
        else        ((float*)C)[row*(size_t)N + col] = acc[mf][nf][r];
      }
}

// ---------------- 128x128 m97-structure GEMM (kept for GRU input, N=256) ----------------
template<int CB>
__global__ __launch_bounds__(256) void gemm_bt_kernel(const u16* __restrict__ A, const u16* __restrict__ BT,
                                                      void* __restrict__ C, int M, int N, int K)
{
  __shared__ u16 As[128*32];
  __shared__ u16 Bs[128*32];
  const int tid = threadIdx.x;
  const int wave = tid >> 6, lane = tid & 63;
  const int mblocks = M >> 7;
  const int mb = blockIdx.x % mblocks;
  const int nb = blockIdx.x / mblocks;
  const int lr = lane >> 2;
  const int lc = (lane & 3) << 3;
  const u16* Ag0 = A  + (size_t)(mb*128 + wave*16 + lr)*K + lc;
  const u16* Bg0 = BT + (size_t)(nb*128 + wave*16 + lr)*K + lc;
  const u16* Ag1 = Ag0 + (size_t)64*K;
  const u16* Bg1 = Bg0 + (size_t)64*K;
  u16* lA0 = &As[(wave*16)*32];
  u16* lA1 = &As[(wave*16+64)*32];
  u16* lB0 = &Bs[(wave*16)*32];
  u16* lB1 = &Bs[(wave*16+64)*32];
  const int wm = (wave >> 1)*64, wn = (wave & 1)*64;
  const int fr = lane & 15, fk = (lane >> 4) << 3;
  f32x4 acc[4][4] = {};
  for (int kt = 0; kt < K; kt += 32){
    __syncthreads();
    gload16(Ag0 + kt, lA0);
    gload16(Ag1 + kt, lA1);
    gload16(Bg0 + kt, lB0);
    gload16(Bg1 + kt, lB1);
    __syncthreads();
    short8 af[4], bfr[4];
#pragma unroll
    for (int i=0;i<4;++i) af[i]  = *(const short8*)&As[(wm + i*16 + fr)*32 + fk];
#pragma unroll
    for (int j=0;j<4;++j) bfr[j] = *(const short8*)&Bs[(wn + j*16 + fr)*32 + fk];
#pragma unroll
    for (int i=0;i<4;++i)
#pragma unroll
      for (int j=0;j<4;++j)
        acc[i][j] = mfma_bf16(af[i], bfr[j], acc[i][j]);
  }
  const int cr = (lane >> 4) << 2, cc = lane & 15;
#pragma unroll
  for (int i=0;i<4;++i)
#pragma unroll
    for (int j=0;j<4;++j)
#pragma unroll
      for (int r=0;r<4;++r){
        const size_t row = (size_t)(mb*128 + wm + i*16 + cr + r);
        const size_t col = (size_t)(nb*128 + wn + j*16 + cc);
        if (CB == 0) ((u16*)C)[row*(size_t)N + col] = f2bf(acc[i][j][r]);
        else        ((float*)C)[row*(size_t)N + col] = acc[i][j][r];
      }
}

// ---------------- attention: per (b,h) block, T=32, dh=512 ----------------
__global__ __launch_bounds__(256) void attn_kernel(const u16* __restrict__ QKV, u16* __restrict__ CTX)
{
  const int b = blockIdx.x >> 2, h = blockIdx.x & 3;
  const int tid = threadIdx.x;
  const int wave = tid >> 6, lane = tid & 63;
  __shared__ float spart[4][32][33];
  __shared__ float sm[32][33];
  __shared__ float rowinv[32];
  __shared__ u16 pb[32][40];
  __shared__ u16 vt[512][40];   // v^T : vt[d][t2]

  {
    const int t2 = tid >> 3;
    const size_t vbase = ((size_t)(b*32 + t2))*6144 + 4096 + h*512;
#pragma unroll
    for (int i = 0; i < 16; ++i){
      int d = (tid & 7)*64 + i*4;
      const u16* p = &QKV[vbase + d];
      vt[d+0][t2] = p[0]; vt[d+1][t2] = p[1]; vt[d+2][t2] = p[2]; vt[d+3][t2] = p[3];
    }
  }
  const int fr = lane & 15, fk = (lane >> 4) << 3;
  f32x4 sacc[2][2] = {};
  const size_t qrow = ((size_t)(b*32))*6144 + h*512;
#pragma unroll
  for (int kk = 0; kk < 4; ++kk){
    const int kof = wave*128 + kk*32 + fk;
    short8 qf0 = *(const short8*)&QKV[qrow + (size_t)fr*6144 + kof];
    short8 qf1 = *(const short8*)&QKV[qrow + (size_t)(fr+16)*6144 + kof];
    short8 kf0 = *(const short8*)&QKV[qrow + 2048 + (size_t)fr*6144 + kof];
    short8 kf1 = *(const short8*)&QKV[qrow + 2048 + (size_t)(fr+16)*6144 + kof];
    sacc[0][0] = mfma_bf16(qf0, kf0, sacc[0][0]);
    sacc[0][1] = mfma_bf16(qf0, kf1, sacc[0][1]);
    sacc[1][0] = mfma_bf16(qf1, kf0, sacc[1][0]);
    sacc[1][1] = mfma_bf16(qf1, kf1, sacc[1][1]);
  }
  const int cr = (lane >> 4) << 2, cc = lane & 15;
#pragma unroll
  for (int i=0;i<2;++i)
#pragma unroll
    for (int j=0;j<2;++j)
#pragma unroll
      for (int r=0;r<4;++r) spart[wave][i*16+cr+r][j*16+cc] = sacc[i][j][r];
  __syncthreads();
  const float scl = 0.04419417382415922f;  // 512^-0.5
  for (int e = tid; e < 1024; e += 256){
    int r = e >> 5, c = e & 31;
    sm[r][c] = (spart[0][r][c]+spart[1][r][c]+spart[2][r][c]+spart[3][r][c])*scl;
  }
  __syncthreads();
  if (tid < 32){
    float m = -1e30f;
    for (int c=0;c<32;++c) m = fmaxf(m, sm[tid][c]);
    float s = 0;
    for (int c=0;c<32;++c){ float e = __expf(sm[tid][c]-m); sm[tid][c] = e; s += e; }
    rowinv[tid] = 1.f/s;
  }
  __syncthreads();
  for (int e = tid; e < 1024; e += 256){
    int r = e>>5, c = e&31;
    pb[r][c] = f2bf(sm[r][c]*rowinv[r]);
  }
  __syncthreads();
  f32x4 cacc[2][8] = {};
  short8 pf0 = *(const short8*)&pb[fr][fk];
  short8 pf1 = *(const short8*)&pb[fr+16][fk];
#pragma unroll
  for (int j=0;j<8;++j){
    short8 vf = *(const short8*)&vt[wave*128 + j*16 + fr][fk];
    cacc[0][j] = mfma_bf16(pf0, vf, cacc[0][j]);
    cacc[1][j] = mfma_bf16(pf1, vf, cacc[1][j]);
  }
#pragma unroll
  for (int i=0;i<2;++i)
#pragma unroll
    for (int j=0;j<8;++j)
#pragma unroll
      for (int r=0;r<4;++r){
        int t1 = i*16 + cr + r;
        int d  = wave*128 + j*16 + cc;
        CTX[((size_t)(b*32+t1))*2048 + h*512 + d] = f2bf(cacc[i][j][r]);
      }
}

// ---------------- residual + bias + LayerNorm -> h_ln bf16 ----------------
__global__ __launch_bounds__(256) void ln_kernel(const u16* __restrict__ OUT, const u16* __restrict__ YS,
                                                 const float* __restrict__ bfv, const float* __restrict__ lng,
                                                 const float* __restrict__ lnb, u16* __restrict__ HLN)
{
  const int row = blockIdx.x, tid = threadIdx.x;
  const size_t base = (size_t)row*2048 + tid*8;
  short8 o8 = *(const short8*)&OUT[base];
  short8 y8 = *(const short8*)&YS[base];
  float hv[8]; float s = 0;
#pragma unroll
  for (int e=0;e<8;++e){ float v = bf2f((u16)o8[e]) + bf2f((u16)y8[e]) + bfv[tid*8+e]; hv[e]=v; s += v; }
  __shared__ float red[4];
#pragma unroll
  for (int off=32; off; off>>=1) s += __shfl_down(s, off, 64);
  if ((tid&63)==0) red[tid>>6] = s;
  __syncthreads();
  const float mu = (red[0]+red[1]+red[2]+red[3]) * (1.f/2048.f);
  float s2 = 0;
#pragma unroll
  for (int e=0;e<8;++e){ float d = hv[e]-mu; s2 += d*d; }
  __syncthreads();
#pragma unroll
  for (int off=32; off; off>>=1) s2 += __shfl_down(s2, off, 64);
  if ((tid&63)==0) red[tid>>6] = s2;
  __syncthreads();
  const float rstd = rsqrtf((red[0]+red[1]+red[2]+red[3])*(1.f/2048.f) + 1e-5f);
  short8 w;
#pragma unroll
  for (int e=0;e<8;++e) w[e] = (short)f2bf((hv[e]-mu)*rstd*lng[tid*8+e] + lnb[tid*8+e]);
  *(short8*)&HLN[base] = w;
}

// ---------------- GRU scan ----------------
__global__ __launch_bounds__(256) void gru_kernel(const float* __restrict__ GI, const float* __restrict__ Whh,
                                                  const float* __restrict__ bih, const float* __restrict__ bhh,
                                                  float* __restrict__ OUTF)
{
  const int b = blockIdx.x, tid = threadIdx.x;
  __shared__ float w[192*65];
  __shared__ float hprev[64];
  __shared__ float gh[192];
#pragma unroll
  for (int i=0;i<48;++i){ int idx = tid + i*256; w[(idx>>6)*65 + (idx&63)] = Whh[idx]; }
  if (tid < 64) hprev[tid] = 0.f;
  const float bh_ = (tid<192) ? bhh[tid] : 0.f;
  __syncthreads();
  for (int t=0;t<32;++t){
    if (tid < 192){
      float s = bh_;
      const float* wr = &w[tid*65];
#pragma unroll 8
      for (int g=0; g<64; ++g) s += wr[g]*hprev[g];
      gh[tid] = s;
    }
    __syncthreads();
    if (tid < 64){
      const float* gi = GI + ((size_t)(b*32 + t))*256;
      float r  = sigmoidf_(gi[tid]     + bih[tid]     + gh[tid]);
      float z  = sigmoidf_(gi[tid+64]  + bih[tid+64]  + gh[tid+64]);
      float n  = tanhf_(gi[tid+128] + bih[tid+128] + r*gh[tid+128]);
      float hn = (1.f - z)*n + z*hprev[tid];
      hprev[tid] = hn;
      OUTF[(size_t)b*2048 + t*64 + tid] = sigmoidf_(hn);
    }
    __syncthreads();
  }
}

// ---------------- heads ----------------
__global__ __launch_bounds__(256) void head_kernel(const float* __restrict__ OUTF, const float* __restrict__ linW,
                                                   const float* __restrict__ linb, const float* __restrict__ clsW,
                                                   const float* __restrict__ clsb, float* __restrict__ outp)
{
  const int b = blockIdx.x, tid = threadIdx.x;
  __shared__ float row[2048];
  __shared__ float pr[128];
  __shared__ float part[256];
  __shared__ float rn;
#pragma unroll
  for (int i=0;i<8;++i) row[tid + i*256] = OUTF[(size_t)b*2048 + tid + i*256];
  __syncthreads();
  {
    const int j = tid & 127, half = tid >> 7;
    const float* wr = linW + (size_t)j*2048 + half*1024;
    const float* xr = &row[half*1024];
    float s = 0;
    for (int k=0;k<1024;++k) s += xr[k]*wr[k];
    part[tid] = s;
  }
  __syncthreads();
  if (tid < 128){
    float v = part[tid] + part[tid+128] + linb[tid];
    v = sigmoidf_(v);
    pr[tid] = v;
    part[tid] = v*v;
  }
  __syncthreads();
  if (tid == 0){
    float ss = 0;
    for (int i2=0;i2<128;++i2) ss += part[i2];
    rn = 1.f/fmaxf(sqrtf(ss), 1e-12f);
  }
  __syncthreads();
  if (tid < 128) outp[(size_t)b*128 + tid] = pr[tid]*rn;
  if (tid < 192){
    const int c = tid >> 6, l = tid & 63;
    const float* wr = clsW + (size_t)c*2048;
    float s = 0;
    for (int k=l; k<2048; k+=64) s += row[k]*wr[k];
#pragma unroll
    for (int off=32; off; off>>=1) s += __shfl_down(s, off, 64);
    if (l == 0) outp[65536 + (size_t)b*3 + c] = sigmoidf_(s + clsb[c]);
  }
}

// ---------------- launch ----------------
extern "C" void kernel_launch(void* const* d_in, const int* in_sizes, int n_in,
                              void* d_out, int out_size, void* d_ws, size_t ws_size,
                              hipStream_t stream) {
  const float* x    = (const float*)d_in[0];
  const float* Aadj = (const float*)d_in[1];
  const float* chbW = (const float*)d_in[2];
  const float* bn1g = (const float*)d_in[3];
  const float* bn1b = (const float*)d_in[4];
  const float* bn2g = (const float*)d_in[5];
  const float* bn2b = (const float*)d_in[6];
  const float* Wq   = (const float*)d_in[7];
  const float* Wk   = (const float*)d_in[8];
  const float* Wv   = (const float*)d_in[9];
  const float* Wf   = (const float*)d_in[10];
  const float* bfv  = (const float*)d_in[11];
  const float* lng  = (const float*)d_in[12];
  const float* lnb  = (const float*)d_in[13];
  const float* Wih  = (const float*)d_in[14];
  const float* Whh  = (const float*)d_in[15];
  const float* bih  = (const float*)d_in[16];
  const float* bhh  = (const float*)d_in[17];
  const float* linW = (const float*)d_in[18];
  const float* linb = (const float*)d_in[19];
  const float* clsW = (const float*)d_in[20];
  const float* clsb = (const float*)d_in[21];

  char* ws = (char*)d_ws;
  u16*   Rb    = (u16*)(ws + OFF_A);
  u16*   OUTB  = (u16*)(ws + OFF_A);
  u16*   YSEQ  = (u16*)(ws + OFF_B);
  u16*   QKV   = (u16*)(ws + OFF_C);
  u16*   CTX   = (u16*)(ws + OFF_D);
  u16*   HLN   = (u16*)(ws + OFF_D);
  u16*   WqkvT = (u16*)(ws + OFF_E);
  u16*   WfT   = (u16*)(ws + OFF_WFT);
  u16*   WihT  = (u16*)(ws + OFF_WIH);
  float* Lhat  = (float*)(ws + OFF_LHAT);
  float* b1p   = (float*)(ws + OFF_B1P);
  float* b1s   = (float*)(ws + OFF_B1S);
  float* b2p   = (float*)(ws + OFF_B2P);
  float* b2s   = (float*)(ws + OFF_B2S);
  float* GI    = (float*)(ws + OFF_GI);
  float* OUTF  = (float*)(ws + OFF_OUTF);

  wtrans_kernel<<<dim3(32,32,4), 256, 0, stream>>>(Wq, Wk, Wv, Wf, WqkvT, WfT);
  wih_kernel<<<dim3(256), 256, 0, stream>>>(Wih, WihT);
  bn1_part_kernel<<<dim3(32,64), 256, 0, stream>>>(x, b1p);
  bn1_fin_kernel<<<dim3(32), 256, 0, stream>>>(b1p, bn1g, bn1b, b1s);
  lap_kernel<<<dim3(32), 256, 0, stream>>>(Aadj, Lhat);
  cheby_kernel<<<dim3(8192), 256, 0, stream>>>(x, Lhat, chbW, b1s, Rb, b2p);
  bn2_fin_kernel<<<dim3(32), 256, 0, stream>>>(b2p, bn2g, bn2b, b2s);
  bn2apply_kernel<<<dim3(16384), 256, 0, stream>>>(Rb, b2s, YSEQ);
  gemm256_kernel<0><<<dim3(1536), 512, 0, stream>>>(YSEQ, WqkvT, (void*)QKV, 16384, 6144, 2048);
  attn_kernel<<<dim3(2048), 256, 0, stream>>>(QKV, CTX);
  gemm256_kernel<0><<<dim3(512), 512, 0, stream>>>(CTX, WfT, (void*)OUTB, 16384, 2048, 2048);
  ln_kernel<<<dim3(16384), 256, 0, stream>>>(OUTB, YSEQ, bfv, lng, lnb, HLN);
  gemm_bt_kernel<1><<<dim3(256), 256, 0, stream>>>(HLN, WihT, (void*)GI, 16384, 256, 2048);
  gru_kernel<<<dim3(512), 256, 0, stream>>>(GI, Whh, bih, bhh, OUTF);
  head_kernel<<<dim3(512), 256, 0, stream>>>(OUTF, linW, linb, clsW, clsb, (float*)d_out);
}

// Round 4
// 982.266 us; speedup vs baseline: 6.1559x; 1.2359x over previous
//
#include <hip/hip_runtime.h>
#include <hip/hip_bf16.h>

typedef unsigned short u16;
typedef __attribute__((ext_vector_type(8))) short short8;   // 8 x bf16 (4 VGPRs)
typedef __attribute__((ext_vector_type(4))) short short4_;  // 4 x bf16
typedef __attribute__((ext_vector_type(4))) float f32x4;

// ---------------- helpers ----------------
__device__ __forceinline__ u16 f2bf(float f){
  union { float fv; unsigned int u; } v; v.fv = f;
  unsigned int u = v.u;
  u = u + 0x7FFFu + ((u >> 16) & 1u);   // RNE
  return (u16)(u >> 16);
}
__device__ __forceinline__ float bf2f(u16 h){
  union { unsigned int u; float fv; } v; v.u = ((unsigned int)h) << 16; return v.fv;
}
__device__ __forceinline__ float sigmoidf_(float x){ return 1.f/(1.f + __expf(-x)); }
__device__ __forceinline__ float tanhf_(float x){ return 2.f/(1.f + __expf(-2.f*x)) - 1.f; }

__device__ __forceinline__ void gload16(const void* g, void* l){
  __builtin_amdgcn_global_load_lds(
      (const __attribute__((address_space(1))) void*)g,
      (__attribute__((address_space(3))) void*)l, 16, 0, 0);
}
__device__ __forceinline__ f32x4 mfma_bf16(short8 a, short8 b, f32x4 c){
  return __builtin_amdgcn_mfma_f32_16x16x32_bf16(a, b, c, 0, 0, 0);
}

#define ASM_VMCNT2 asm volatile("s_waitcnt vmcnt(2)" ::: "memory")
#define ASM_VMCNT0 asm volatile("s_waitcnt vmcnt(0)" ::: "memory")
#define ASM_LGK0   asm volatile("s_waitcnt lgkmcnt(0)" ::: "memory")
#define SCHB       __builtin_amdgcn_sched_barrier(0)
#define SBAR       do { asm volatile("" ::: "memory"); __builtin_amdgcn_s_barrier(); asm volatile("" ::: "memory"); } while(0)

// ---------------- workspace layout (bytes) ----------------
constexpr size_t OFF_A    = 0;                       // R bf16 [32][512][64][32] ; later: attn-out bf16 [16384][2048]
constexpr size_t OFF_B    = 67108864;                // y_seq bf16 [16384][2048]
constexpr size_t OFF_C    = OFF_B + 67108864;        // WT2 bf16 (pre-GEMM) ; QKV bf16 [16384][6144] ; later GI/OUTF f32
constexpr size_t OFF_D    = OFF_C + 201326592;       // ctx bf16 [16384][2048] ; later: h_ln bf16
constexpr size_t OFF_E    = OFF_D + 67108864;        // WqkvT bf16 [6144][2048]
constexpr size_t OFF_WFT  = OFF_E + 25165824;        // WfT bf16 [2048][2048]
constexpr size_t OFF_WIH  = OFF_WFT + 8388608;       // WihT bf16 [256][2048] (rows 192..255 zero)
constexpr size_t OFF_LHAT = OFF_WIH + 1048576;       // Tcat bf16 [32][64][256] (1 MB, overlays old Lhat+b1p)
constexpr size_t OFF_B1P  = OFF_LHAT + 524288;       // bn1 partials f32 (dead before lap2 writes Tcat)
constexpr size_t OFF_B1S  = OFF_B1P + 524288;        // bn1 scale/shift f32 [32][32][2]
constexpr size_t OFF_B2P  = OFF_B1S + 8192;          // bn2 partials f32 [32][512][32][2]
constexpr size_t OFF_B2S  = OFF_B2P + 4194304;       // bn2 scale/shift f32 [32][32][2]
constexpr size_t OFF_TC   = OFF_LHAT;                // Tcat bf16 32*16384*2 = 1 MB (after bn1_fin)
constexpr size_t OFF_WT2  = OFF_C;                   // WTg bf16 [32][4][32][32] = 256 KB (dead before QKV GEMM)
constexpr size_t OFF_GI   = OFF_C;                   // f32 [16384][256]
constexpr size_t OFF_OUTF = OFF_C + 16777216;        // f32 [512][2048]

// ---------------- weight transpose: W[k][n] f32 -> WT[n][k] bf16 ----------------
__global__ __launch_bounds__(256) void wtrans_kernel(const float* __restrict__ Wq, const float* __restrict__ Wk,
                                                     const float* __restrict__ Wv, const float* __restrict__ Wf,
                                                     u16* __restrict__ WqkvT, u16* __restrict__ WfT)
{
  const int k0 = blockIdx.x*64, n0 = blockIdx.y*64, z = blockIdx.z;
  const float* src = (z==0)?Wq:(z==1)?Wk:(z==2)?Wv:Wf;
  u16* dst = (z<3) ? (WqkvT + (size_t)z*2048*2048) : WfT;
  __shared__ float tile[64][65];
  const int c = threadIdx.x & 63, r0 = threadIdx.x >> 6;
#pragma unroll
  for (int i=0;i<16;++i){ int r = r0 + i*4; tile[r][c] = src[(size_t)(k0+r)*2048 + n0 + c]; }
  __syncthreads();
#pragma unroll
  for (int i=0;i<16;++i){ int r = r0 + i*4; dst[(size_t)(n0+r)*2048 + k0 + c] = f2bf(tile[c][r]); }
}

__global__ __launch_bounds__(256) void wih_kernel(const float* __restrict__ Wih, u16* __restrict__ WT)
{
  const int row = blockIdx.x, tid = threadIdx.x;
#pragma unroll
  for (int i=0;i<8;++i){ int col = tid + i*256;
    float v = (row < 192) ? Wih[(size_t)row*2048 + col] : 0.f;
    WT[(size_t)row*2048 + col] = f2bf(v);
  }
}

// ---------------- BN1 stats (two-stage, deterministic) ----------------
__global__ __launch_bounds__(256) void bn1_part_kernel(const float* __restrict__ x, float* __restrict__ part)
{
  const int t = blockIdx.x, sl = blockIdx.y;
  const int f = threadIdx.x & 31, grp = threadIdx.x >> 5;
  float s = 0.f, ss = 0.f;
  for (int bb = 0; bb < 8; ++bb){
    const int b = sl*8 + bb;
    const float* xp = x + ((size_t)(b*32 + t))*2048;
    for (int i = 0; i < 8; ++i){
      int n = i*8 + grp;
      float v = xp[n*32 + f];
      s += v; ss += v*v;
    }
  }
  __shared__ float red[8][32][2];
  red[grp][f][0] = s; red[grp][f][1] = ss;
  __syncthreads();
  if (threadIdx.x < 32){
    float S=0, SS=0;
    for (int g=0; g<8; ++g){ S += red[g][threadIdx.x][0]; SS += red[g][threadIdx.x][1]; }
    size_t o = (((size_t)t*64 + sl)*32 + threadIdx.x)*2;
    part[o] = S; part[o+1] = SS;
  }
}

__global__ __launch_bounds__(256) void bn1_fin_kernel(const float* __restrict__ part, const float* __restrict__ g1,
                                                      const float* __restrict__ b1, float* __restrict__ out)
{
  const int t = blockIdx.x;
  const int f = threadIdx.x & 31, grp = threadIdx.x >> 5;
  float s=0, ss=0;
  for (int sl = grp; sl < 64; sl += 8){
    size_t o = (((size_t)t*64 + sl)*32 + f)*2;
    s += part[o]; ss += part[o+1];
  }
  __shared__ float red[8][32][2];
  red[grp][f][0]=s; red[grp][f][1]=ss;
  __syncthreads();
  if (threadIdx.x < 32){
    float S=0, SS=0;
    for (int g=0; g<8; ++g){ S+=red[g][threadIdx.x][0]; SS+=red[g][threadIdx.x][1]; }
    float mean = S*(1.f/32768.f);
    float var  = SS*(1.f/32768.f) - mean*mean;
    float sc   = g1[t*32+threadIdx.x]*rsqrtf(var + 1e-5f);
    out[(t*32+threadIdx.x)*2]   = sc;
    out[(t*32+threadIdx.x)*2+1] = b1[t*32+threadIdx.x] - mean*sc;
  }
}

// ---------------- lap2: per-t Laplacian + Chebyshev basis T0..T3 (bf16) + W^T (bf16) ----------------
// Tcat[t][n][k*64+m] = T_k(Lhat)[n][m] ; WTg[t][k][fo][f] = chebW[t][k][f][fo]
__global__ __launch_bounds__(256) void lap2_kernel(const float* __restrict__ A, const float* __restrict__ chebW,
                                                   u16* __restrict__ Tcat, u16* __restrict__ WTg)
{
  const int t = blockIdx.x, tid = threadIdx.x;
  __shared__ float Ar[64][68];
  __shared__ float L1[64][68];
  __shared__ float T2s[64][68];
  __shared__ float dr[64];
#pragma unroll
  for (int i=0;i<16;++i){ int idx = tid + i*256; int r = idx>>6, c = idx&63;
    float v = A[(size_t)t*4096 + idx]; v = fmaxf(v, 0.f); if (r==c) v = 0.f;
    Ar[r][c] = v; }
  __syncthreads();
  if (tid < 64){
    float s = 0;
    for (int c2=0;c2<64;++c2) s += Ar[tid][c2] + Ar[c2][tid];
    dr[tid] = rsqrtf(s + 1e-10f);
  }
  __syncthreads();
#pragma unroll
  for (int i=0;i<16;++i){ int idx = tid + i*256; int r = idx>>6, c = idx&63;
    L1[r][c] = -(Ar[r][c] + Ar[c][r]) * dr[r] * dr[c];
  }
  __syncthreads();
  const int row = tid >> 2, c0 = (tid & 3) << 4;
  // T2 = 2 L^2 - I
  float a2[16];
#pragma unroll
  for (int j=0;j<16;++j) a2[j] = 0.f;
#pragma unroll 4
  for (int m=0;m<64;++m){
    float lv = L1[row][m];
#pragma unroll
    for (int j=0;j<16;++j) a2[j] += lv*L1[m][c0+j];
  }
#pragma unroll
  for (int j=0;j<16;++j) T2s[row][c0+j] = 2.f*a2[j] - ((row==c0+j)?1.f:0.f);
  __syncthreads();
  // T3 = 2 L T2 - L
  float a3[16];
#pragma unroll
  for (int j=0;j<16;++j) a3[j] = 0.f;
#pragma unroll 4
  for (int m=0;m<64;++m){
    float lv = L1[row][m];
#pragma unroll
    for (int j=0;j<16;++j) a3[j] += lv*T2s[m][c0+j];
  }
  u16* tb = Tcat + (size_t)t*16384 + row*256;
#pragma unroll
  for (int j=0;j<16;++j){
    int c = c0 + j;
    tb[c]       = f2bf((row==c)?1.f:0.f);
    tb[64 + c]  = f2bf(L1[row][c]);
    tb[128 + c] = f2bf(T2s[row][c]);
    tb[192 + c] = f2bf(2.f*a3[j] - L1[row][c]);
  }
  // W transpose
#pragma unroll
  for (int i=0;i<16;++i){
    int idx = tid + i*256;
    int k = idx>>10, f = (idx>>5)&31, fo = idx&31;
    WTg[(size_t)t*4096 + k*1024 + fo*32 + f] = f2bf(chebW[(size_t)t*4096 + idx]);
  }
}

// ---------------- Chebyshev conv via MFMA ----------------
// Per block: fixed t, 8 b's, 4 waves. Per b:
//   step1 (wave=k): G_k[m][fo] = X[m][f] @ W_k[f][fo]  (8 MFMA, K=32) -> Gt[k][fo][m] bf16
//   step2 (wave=ntile): R[n][fo] = Tcat[n][256] . Gt-cat[fo][256]    (16 MFMA, K=256)
// All LDS strides 16B-aligned, <=2-way bank aliasing (free).
__global__ __launch_bounds__(256) void cheby_kernel(const float* __restrict__ x, const u16* __restrict__ Tcat,
                                                    const u16* __restrict__ WTg, const float* __restrict__ bn1ss,
                                                    u16* __restrict__ Rb, float* __restrict__ bn2p)
{
  const int t = blockIdx.x >> 6, grp = blockIdx.x & 63, b0 = grp*8;
  const int tid = threadIdx.x, wid = tid >> 6, lane = tid & 63;
  const int fr = lane & 15, fk = (lane >> 4) << 3;
  const int cc = lane & 15, cr = (lane >> 4) << 2;

  __shared__ u16 Tc[64][264];    // rows 528B, 2-way banks
  __shared__ u16 Wt[128][40];    // [k*32+fo][f], rows 80B
  __shared__ u16 Xs[64][40];     // [m][f]
  __shared__ u16 Gt[128][72];    // [k*32+fo][m], rows 144B
  __shared__ float red[4][32][2];
  __shared__ float scs[64];

  if (tid < 64) scs[tid] = bn1ss[t*64 + tid];
  {
    const u16* src = Tcat + (size_t)t*16384;
#pragma unroll
    for (int i=0;i<8;++i){ int idx = tid + i*256; int r = idx>>5, c8 = (idx&31)<<3;
      *(short8*)&Tc[r][c8] = *(const short8*)&src[r*256 + c8]; }
  }
  {
    const u16* src = WTg + (size_t)t*4096;
#pragma unroll
    for (int i=0;i<2;++i){ int idx = tid + i*256; int r = idx>>2, c8 = (idx&3)<<3;
      *(short8*)&Wt[r][c8] = *(const short8*)&src[r*32 + c8]; }
  }
  __syncthreads();

  for (int bb=0; bb<8; ++bb){
    const int b = b0 + bb;
    { // stage X = bn1(x_b) -> bf16
      const float* xr = x + ((size_t)(b*32 + t))*2048;
      f32x4 v0 = *(const f32x4*)&xr[tid*8];
      f32x4 v1 = *(const f32x4*)&xr[tid*8+4];
      const int fb = (tid*8)&31;
      short8 w;
#pragma unroll
      for (int e=0;e<4;++e){
        w[e]   = (short)f2bf(v0[e]*scs[2*(fb+e)]   + scs[2*(fb+e)+1]);
        w[e+4] = (short)f2bf(v1[e]*scs[2*(fb+4+e)] + scs[2*(fb+4+e)+1]);
      }
      *(short8*)&Xs[tid>>2][(tid&3)<<3] = w;
    }
    __syncthreads();
    { // step1: wave wid computes G_{k=wid}
      f32x4 g[4][2] = {};
      short8 xa[4], wb[2];
#pragma unroll
      for (int m2=0;m2<4;++m2) xa[m2] = *(const short8*)&Xs[m2*16 + fr][fk];
#pragma unroll
      for (int j=0;j<2;++j)    wb[j]  = *(const short8*)&Wt[wid*32 + j*16 + fr][fk];
#pragma unroll
      for (int m2=0;m2<4;++m2)
#pragma unroll
        for (int j=0;j<2;++j) g[m2][j] = mfma_bf16(xa[m2], wb[j], g[m2][j]);
#pragma unroll
      for (int m2=0;m2<4;++m2)
#pragma unroll
        for (int j=0;j<2;++j){
          short4_ q;
#pragma unroll
          for (int r=0;r<4;++r) q[r] = (short)f2bf(g[m2][j][r]);
          *(short4_*)&Gt[wid*32 + j*16 + cc][m2*16 + cr] = q;
        }
    }
    __syncthreads();
    // step2: wave wid = n-tile
    f32x4 racc[2] = {};
#pragma unroll
    for (int ks=0; ks<8; ++ks){
      short8 ta  = *(const short8*)&Tc[wid*16 + fr][ks*32 + fk];
      short8 gb0 = *(const short8*)&Gt[(ks>>1)*32 + fr][(ks&1)*32 + fk];
      short8 gb1 = *(const short8*)&Gt[(ks>>1)*32 + 16 + fr][(ks&1)*32 + fk];
      racc[0] = mfma_bf16(ta, gb0, racc[0]);
      racc[1] = mfma_bf16(ta, gb1, racc[1]);
    }
    // relu + write R + bn2 partials
    u16* rrow = Rb + ((size_t)(t*512 + b))*2048;
    float sev[2], sqv[2];
#pragma unroll
    for (int j=0;j<2;++j){
      float s1=0.f, s2=0.f;
#pragma unroll
      for (int r=0;r<4;++r){
        float v = fmaxf(racc[j][r], 0.f);
        rrow[(wid*16 + cr + r)*32 + j*16 + cc] = f2bf(v);
        s1 += v; s2 += v*v;
      }
      sev[j]=s1; sqv[j]=s2;
    }
#pragma unroll
    for (int j=0;j<2;++j){
      sev[j] += __shfl_xor(sev[j], 16, 64); sev[j] += __shfl_xor(sev[j], 32, 64);
      sqv[j] += __shfl_xor(sqv[j], 16, 64); sqv[j] += __shfl_xor(sqv[j], 32, 64);
    }
    if (lane < 16){
#pragma unroll
      for (int j=0;j<2;++j){ red[wid][j*16+cc][0] = sev[j]; red[wid][j*16+cc][1] = sqv[j]; }
    }
    __syncthreads();
    if (tid < 64){
      int f = tid & 31, c = tid >> 5;
      bn2p[((size_t)(t*512+b)*32 + f)*2 + c] = red[0][f][c]+red[1][f][c]+red[2][f][c]+red[3][f][c];
    }
    __syncthreads();
  }
}

__global__ __launch_bounds__(256) void bn2_fin_kernel(const float* __restrict__ part, const float* __restrict__ g2,
                                                      const float* __restrict__ b2, float* __restrict__ out)
{
  const int t = blockIdx.x;
  const int f = threadIdx.x & 31, grp = threadIdx.x >> 5;
  float s=0, ss=0;
  for (int b = grp; b < 512; b += 8){
    size_t o = ((size_t)(t*512+b)*32 + f)*2;
    s += part[o]; ss += part[o+1];
  }
  __shared__ float red[8][32][2];
  red[grp][f][0]=s; red[grp][f][1]=ss;
  __syncthreads();
  if (threadIdx.x < 32){
    float S=0, SS=0;
    for (int g=0; g<8; ++g){ S+=red[g][threadIdx.x][0]; SS+=red[g][threadIdx.x][1]; }
    float mean = S*(1.f/32768.f);
    float var  = SS*(1.f/32768.f) - mean*mean;
    float scv  = g2[t*32+threadIdx.x]*rsqrtf(var + 1e-5f);
    out[(t*32+threadIdx.x)*2]   = scv;
    out[(t*32+threadIdx.x)*2+1] = b2[t*32+threadIdx.x] - mean*scv;
  }
}

// ---------------- BN2 apply + sigmoid + permute ----------------
__global__ __launch_bounds__(256) void bn2apply_kernel(const u16* __restrict__ Rb, const float* __restrict__ ss,
                                                       u16* __restrict__ YS)
{
  const int t = blockIdx.x >> 9, b = blockIdx.x & 511, tid = threadIdx.x;
  __shared__ float scs[64];
  if (tid < 64) scs[tid] = ss[t*64 + tid];
  __syncthreads();
  const int n = tid >> 2, f0 = (tid & 3) << 3;
  short8 rv = *(const short8*)&Rb[((size_t)(t*512+b))*2048 + tid*8];
  short8 w;
#pragma unroll
  for (int e=0;e<8;++e){
    int f = f0 + e;
    float v = bf2f((u16)rv[e])*scs[f*2] + scs[f*2+1];
    w[e] = (short)f2bf(sigmoidf_(v));
  }
  *(short8*)&YS[((size_t)(b*32 + (n>>1)))*2048 + (n&1)*1024 + t*32 + f0] = w;
}

// ============ 256x256 8-phase bf16 MFMA GEMM (T1+T2+T3+T4+T5) ============
template<int CB>   // 0 -> bf16 C, 1 -> f32 C
__global__ __launch_bounds__(512, 2) void gemm256_kernel(const u16* __restrict__ A, const u16* __restrict__ BT,
                                                         void* __restrict__ C, int M, int N, int K)
{
  __shared__ u16 smem[65536];   // 128 KiB
  const int tid = threadIdx.x, wid = tid >> 6, lane = tid & 63;
  const int nwg = gridDim.x, cpx = nwg >> 3;
  const int logical = ((int)blockIdx.x & 7)*cpx + ((int)blockIdx.x >> 3);  // XCD swizzle (nwg%8==0)
  const int MB = M >> 8;
  const int mb = logical % MB, nb = logical / MB;
  const int m0 = mb << 8, n0g = nb << 8;
  const int nkt = K >> 6;
  const int nit = nkt >> 1;

  const int wr = wid >> 2, wc = wid & 3;
  const int fr = lane & 15, fk = (lane >> 4) << 3;
  const int cz0 = fk ^ ((fr & 7) << 3);
  const int cz1 = (32 + fk) ^ ((fr & 7) << 3);
  const int srow = wid*16 + (lane >> 3);
  const int scol = ((lane & 7) ^ (lane >> 3)) << 3;
  const int bhalf = wc >> 1, brow0 = (wc & 1) << 6;

  f32x4 acc[8][4] = {};
  short8 af[4][2], bg[4][2];

#define STG(PTR, R0, DSTB, TK, H) do { if ((TK) < nkt) { \
  const u16* _g = (PTR) + (size_t)((R0) + ((H)<<7) + srow)*(size_t)K + (size_t)(((TK)<<6) + scol); \
  u16* _d = &smem[(DSTB) + ((H)<<13) + (wid<<10)]; \
  gload16(_g, _d); gload16(_g + ((size_t)K<<3), _d + 512); } } while(0)

#define DSA(BUF, QM) { _Pragma("unroll") for(int m2=0;m2<4;++m2){ \
  const u16* _p = &smem[(BUF) + wr*8192 + (((QM)*64 + m2*16 + fr)<<6)]; \
  af[m2][0] = *(const short8*)(_p + cz0); af[m2][1] = *(const short8*)(_p + cz1); } }

#define DSB(BUF, QN) { _Pragma("unroll") for(int n2=0;n2<2;++n2){ \
  const u16* _p = &smem[(BUF) + 16384 + bhalf*8192 + ((brow0 + (QN)*32 + n2*16 + fr)<<6)]; \
  bg[(QN)*2+n2][0] = *(const short8*)(_p + cz0); bg[(QN)*2+n2][1] = *(const short8*)(_p + cz1); } }

#define MMA(QM, QN) { __builtin_amdgcn_s_setprio(1); \
  _Pragma("unroll") for(int m2=0;m2<4;++m2) _Pragma("unroll") for(int n2=0;n2<2;++n2) { \
    acc[(QM)*4+m2][(QN)*2+n2] = mfma_bf16(af[m2][0], bg[(QN)*2+n2][0], acc[(QM)*4+m2][(QN)*2+n2]); \
    acc[(QM)*4+m2][(QN)*2+n2] = mfma_bf16(af[m2][1], bg[(QN)*2+n2][1], acc[(QM)*4+m2][(QN)*2+n2]); } \
  __builtin_amdgcn_s_setprio(0); }

  STG(A,  m0,  0,     0, 0); STG(A,  m0,  0,     0, 1);
  STG(BT, n0g, 16384, 0, 0); STG(BT, n0g, 16384, 0, 1);
  STG(A,  m0,  32768, 1, 0);
  ASM_VMCNT2; SBAR;

  for (int i = 0; i < nit; ++i){
    const int kb = i*2;
    DSA(0, 0); DSB(0, 0);
    STG(A, m0, 32768, kb+1, 1);
    SBAR; ASM_LGK0; SCHB; MMA(0,0); SBAR;
    DSB(0, 1);
    STG(BT, n0g, 49152, kb+1, 0);
    SBAR; ASM_LGK0; SCHB; MMA(0,1); SBAR;
    DSA(0, 1);
    STG(BT, n0g, 49152, kb+1, 1);
    SBAR; ASM_LGK0; SCHB; MMA(1,0); SBAR;
    STG(A, m0, 0, kb+2, 0);
    if (kb + 2 >= nkt) { ASM_VMCNT0; } else { ASM_VMCNT2; }
    SBAR; MMA(1,1); SBAR;
    DSA(32768, 0); DSB(32768, 0);
    STG(A, m0, 0, kb+2, 1);
    SBAR; ASM_LGK0; SCHB; MMA(0,0); SBAR;
    DSB(32768, 1);
    STG(BT, n0g, 16384, kb+2, 0);
    SBAR; ASM_LGK0; SCHB; MMA(0,1); SBAR;
    DSA(32768, 1);
    STG(BT, n0g, 16384, kb+2, 1);
    SBAR; ASM_LGK0; SCHB; MMA(1,0); SBAR;
    STG(A, m0, 32768, kb+3, 0);
    ASM_VMCNT2;
    SBAR; MMA(1,1); SBAR;
  }

#undef STG
#undef DSA
#undef DSB
#undef MMA

  const int cr = (lane >> 4) << 2, cc = lane & 15;
#pragma unroll
  for (int mf=0; mf<8; ++mf)
#pragma unroll
    for (int nf=0; nf<4; ++nf)
#pragma unroll
      for (int r=0; r<4; ++r){
        const size_t row = (size_t)(m0 + wr*128 + mf*16 + cr + r);
        const size_t col = (size_t)(n0g + wc*64 + nf*16 + cc);
        if (CB == 0) ((u16*)C)[row*(size_t)N + col] = f2bf(acc[mf][nf][r]);
        else        ((float*)C)[row*(size_t)N + col] = acc[mf][nf][r];
      }
}

// ---------------- 128x128 m97-structure GEMM (GRU input, N=256) ----------------
template<int CB>
__global__ __launch_bounds__(256) void gemm_bt_kernel(const u16* __restrict__ A, const u16* __restrict__ BT,
                                                      void* __restrict__ C, int M, int N, int K)
{
  __shared__ u16 As[128*32];
  __shared__ u16 Bs[128*32];
  const int tid = threadIdx.x;
  const int wave = tid >> 6, lane = tid & 63;
  const int mblocks = M >> 7;
  const int mb = blockIdx.x % mblocks;
  const int nb = blockIdx.x / mblocks;
  const int lr = lane >> 2;
  const int lc = (lane & 3) << 3;
  const u16* Ag0 = A  + (size_t)(mb*128 + wave*16 + lr)*K + lc;
  const u16* Bg0 = BT + (size_t)(nb*128 + wave*16 + lr)*K + lc;
  const u16* Ag1 = Ag0 + (size_t)64*K;
  const u16* Bg1 = Bg0 + (size_t)64*K;
  u16* lA0 = &As[(wave*16)*32];
  u16* lA1 = &As[(wave*16+64)*32];
  u16* lB0 = &Bs[(wave*16)*32];
  u16* lB1 = &Bs[(wave*16+64)*32];
  const int wm = (wave >> 1)*64, wn = (wave & 1)*64;
  const int fr = lane & 15, fk = (lane >> 4) << 3;
  f32x4 acc[4][4] = {};
  for (int kt = 0; kt < K; kt += 32){
    __syncthreads();
    gload16(Ag0 + kt, lA0);
    gload16(Ag1 + kt, lA1);
    gload16(Bg0 + kt, lB0);
    gload16(Bg1 + kt, lB1);
    __syncthreads();
    short8 af[4], bfr[4];
#pragma unroll
    for (int i=0;i<4;++i) af[i]  = *(const short8*)&As[(wm + i*16 + fr)*32 + fk];
#pragma unroll
    for (int j=0;j<4;++j) bfr[j] = *(const short8*)&Bs[(wn + j*16 + fr)*32 + fk];
#pragma unroll
    for (int i=0;i<4;++i)
#pragma unroll
      for (int j=0;j<4;++j)
        acc[i][j] = mfma_bf16(af[i], bfr[j], acc[i][j]);
  }
  const int cr = (lane >> 4) << 2, cc = lane & 15;
#pragma unroll
  for (int i=0;i<4;++i)
#pragma unroll
    for (int j=0;j<4;++j)
#pragma unroll
      for (int r=0;r<4;++r){
        const size_t row = (size_t)(mb*128 + wm + i*16 + cr + r);
        const size_t col = (size_t)(nb*128 + wn + j*16 + cc);
        if (CB == 0) ((u16*)C)[row*(size_t)N + col] = f2bf(acc[i][j][r]);
        else        ((float*)C)[row*(size_t)N + col] = acc[i][j][r];
      }
}

// ---------------- attention: per (b,h) block, T=32, dh=512 ----------------
__global__ __launch_bounds__(256) void attn_kernel(const u16* __restrict__ QKV, u16* __restrict__ CTX)
{
  const int b = blockIdx.x >> 2, h = blockIdx.x & 3;
  const int tid = threadIdx.x;
  const int wave = tid >> 6, lane = tid & 63;
  __shared__ float spart[4][32][33];
  __shared__ float sm[32][33];
  __shared__ float rowinv[32];
  __shared__ u16 pb[32][40];
  __shared__ u16 vt[512][40];   // v^T : vt[d][t2]

  {
    const int t2 = tid >> 3;
    const size_t vbase = ((size_t)(b*32 + t2))*6144 + 4096 + h*512;
#pragma unroll
    for (int i = 0; i < 16; ++i){
      int d = (tid & 7)*64 + i*4;
      const u16* p = &QKV[vbase + d];
      vt[d+0][t2] = p[0]; vt[d+1][t2] = p[1]; vt[d+2][t2] = p[2]; vt[d+3][t2] = p[3];
    }
  }
  const int fr = lane & 15, fk = (lane >> 4) << 3;
  f32x4 sacc[2][2] = {};
  const size_t qrow = ((size_t)(b*32))*6144 + h*512;
#pragma unroll
  for (int kk = 0; kk < 4; ++kk){
    const int kof = wave*128 + kk*32 + fk;
    short8 qf0 = *(const short8*)&QKV[qrow + (size_t)fr*6144 + kof];
    short8 qf1 = *(const short8*)&QKV[qrow + (size_t)(fr+16)*6144 + kof];
    short8 kf0 = *(const short8*)&QKV[qrow + 2048 + (size_t)fr*6144 + kof];
    short8 kf1 = *(const short8*)&QKV[qrow + 2048 + (size_t)(fr+16)*6144 + kof];
    sacc[0][0] = mfma_bf16(qf0, kf0, sacc[0][0]);
    sacc[0][1] = mfma_bf16(qf0, kf1, sacc[0][1]);
    sacc[1][0] = mfma_bf16(qf1, kf0, sacc[1][0]);
    sacc[1][1] = mfma_bf16(qf1, kf1, sacc[1][1]);
  }
  const int cr = (lane >> 4) << 2, cc = lane & 15;
#pragma unroll
  for (int i=0;i<2;++i)
#pragma unroll
    for (int j=0;j<2;++j)
#pragma unroll
      for (int r=0;r<4;++r) spart[wave][i*16+cr+r][j*16+cc] = sacc[i][j][r];
  __syncthreads();
  const float scl = 0.04419417382415922f;  // 512^-0.5
  for (int e = tid; e < 1024; e += 256){
    int r = e >> 5, c = e & 31;
    sm[r][c] = (spart[0][r][c]+spart[1][r][c]+spart[2][r][c]+spart[3][r][c])*scl;
  }
  __syncthreads();
  if (tid < 32){
    float m = -1e30f;
    for (int c=0;c<32;++c) m = fmaxf(m, sm[tid][c]);
    float s = 0;
    for (int c=0;c<32;++c){ float e = __expf(sm[tid][c]-m); sm[tid][c] = e; s += e; }
    rowinv[tid] = 1.f/s;
  }
  __syncthreads();
  for (int e = tid; e < 1024; e += 256){
    int r = e>>5, c = e&31;
    pb[r][c] = f2bf(sm[r][c]*rowinv[r]);
  }
  __syncthreads();
  f32x4 cacc[2][8] = {};
  short8 pf0 = *(const short8*)&pb[fr][fk];
  short8 pf1 = *(const short8*)&pb[fr+16][fk];
#pragma unroll
  for (int j=0;j<8;++j){
    short8 vf = *(const short8*)&vt[wave*128 + j*16 + fr][fk];
    cacc[0][j] = mfma_bf16(pf0, vf, cacc[0][j]);
    cacc[1][j] = mfma_bf16(pf1, vf, cacc[1][j]);
  }
#pragma unroll
  for (int i=0;i<2;++i)
#pragma unroll
    for (int j=0;j<8;++j)
#pragma unroll
      for (int r=0;r<4;++r){
        int t1 = i*16 + cr + r;
        int d  = wave*128 + j*16 + cc;
        CTX[((size_t)(b*32+t1))*2048 + h*512 + d] = f2bf(cacc[i][j][r]);
      }
}

// ---------------- residual + bias + LayerNorm -> h_ln bf16 ----------------
__global__ __launch_bounds__(256) void ln_kernel(const u16* __restrict__ OUT, const u16* __restrict__ YS,
                                                 const float* __restrict__ bfv, const float* __restrict__ lng,
                                                 const float* __restrict__ lnb, u16* __restrict__ HLN)
{
  const int row = blockIdx.x, tid = threadIdx.x;
  const size_t base = (size_t)row*2048 + tid*8;
  short8 o8 = *(const short8*)&OUT[base];
  short8 y8 = *(const short8*)&YS[base];
  float hv[8]; float s = 0;
#pragma unroll
  for (int e=0;e<8;++e){ float v = bf2f((u16)o8[e]) + bf2f((u16)y8[e]) + bfv[tid*8+e]; hv[e]=v; s += v; }
  __shared__ float red[4];
#pragma unroll
  for (int off=32; off; off>>=1) s += __shfl_down(s, off, 64);
  if ((tid&63)==0) red[tid>>6] = s;
  __syncthreads();
  const float mu = (red[0]+red[1]+red[2]+red[3]) * (1.f/2048.f);
  float s2 = 0;
#pragma unroll
  for (int e=0;e<8;++e){ float d = hv[e]-mu; s2 += d*d; }
  __syncthreads();
#pragma unroll
  for (int off=32; off; off>>=1) s2 += __shfl_down(s2, off, 64);
  if ((tid&63)==0) red[tid>>6] = s2;
  __syncthreads();
  const float rstd = rsqrtf((red[0]+red[1]+red[2]+red[3])*(1.f/2048.f) + 1e-5f);
  short8 w;
#pragma unroll
  for (int e=0;e<8;++e) w[e] = (short)f2bf((hv[e]-mu)*rstd*lng[tid*8+e] + lnb[tid*8+e]);
  *(short8*)&HLN[base] = w;
}

// ---------------- GRU scan ----------------
__global__ __launch_bounds__(256) void gru_kernel(const float* __restrict__ GI, const float* __restrict__ Whh,
                                                  const float* __restrict__ bih, const float* __restrict__ bhh,
                                                  float* __restrict__ OUTF)
{
  const int b = blockIdx.x, tid = threadIdx.x;
  __shared__ float w[192*65];
  __shared__ float hprev[64];
  __shared__ float gh[192];
#pragma unroll
  for (int i=0;i<48;++i){ int idx = tid + i*256; w[(idx>>6)*65 + (idx&63)] = Whh[idx]; }
  if (tid < 64) hprev[tid] = 0.f;
  const float bh_ = (tid<192) ? bhh[tid] : 0.f;
  __syncthreads();
  for (int t=0;t<32;++t){
    if (tid < 192){
      float s = bh_;
      const float* wr = &w[tid*65];
#pragma unroll 8
      for (int g=0; g<64; ++g) s += wr[g]*hprev[g];
      gh[tid] = s;
    }
    __syncthreads();
    if (tid < 64){
      const float* gi = GI + ((size_t)(b*32 + t))*256;
      float r  = sigmoidf_(gi[tid]     + bih[tid]     + gh[tid]);
      float z  = sigmoidf_(gi[tid+64]  + bih[tid+64]  + gh[tid+64]);
      float n  = tanhf_(gi[tid+128] + bih[tid+128] + r*gh[tid+128]);
      float hn = (1.f - z)*n + z*hprev[tid];
      hprev[tid] = hn;
      OUTF[(size_t)b*2048 + t*64 + tid] = sigmoidf_(hn);
    }
    __syncthreads();
  }
}

// ---------------- heads ----------------
__global__ __launch_bounds__(256) void head_kernel(const float* __restrict__ OUTF, const float* __restrict__ linW,
                                                   const float* __restrict__ linb, const float* __restrict__ clsW,
                                                   const float* __restrict__ clsb, float* __restrict__ outp)
{
  const int b = blockIdx.x, tid = threadIdx.x;
  __shared__ float row[2048];
  __shared__ float pr[128];
  __shared__ float part[256];
  __shared__ float rn;
#pragma unroll
  for (int i=0;i<8;++i) row[tid + i*256] = OUTF[(size_t)b*2048 + tid + i*256];
  __syncthreads();
  {
    const int j = tid & 127, half = tid >> 7;
    const float* wr = linW + (size_t)j*2048 + half*1024;
    const float* xr = &row[half*1024];
    float s = 0;
    for (int k=0;k<1024;++k) s += xr[k]*wr[k];
    part[tid] = s;
  }
  __syncthreads();
  if (tid < 128){
    float v = part[tid] + part[tid+128] + linb[tid];
    v = sigmoidf_(v);
    pr[tid] = v;
    part[tid] = v*v;
  }
  __syncthreads();
  if (tid == 0){
    float ss = 0;
    for (int i2=0;i2<128;++i2) ss += part[i2];
    rn = 1.f/fmaxf(sqrtf(ss), 1e-12f);
  }
  __syncthreads();
  if (tid < 128) outp[(size_t)b*128 + tid] = pr[tid]*rn;
  if (tid < 192){
    const int c = tid >> 6, l = tid & 63;
    const float* wr = clsW + (size_t)c*2048;
    float s = 0;
    for (int k=l; k<2048; k+=64) s += row[k]*wr[k];
#pragma unroll
    for (int off=32; off; off>>=1) s += __shfl_down(s, off, 64);
    if (l == 0) outp[65536 + (size_t)b*3 + c] = sigmoidf_(s + clsb[c]);
  }
}

// ---------------- launch ----------------
extern "C" void kernel_launch(void* const* d_in, const int* in_sizes, int n_in,
                              void* d_out, int out_size, void* d_ws, size_t ws_size,
                              hipStream_t stream) {
  const float* x    = (const float*)d_in[0];
  const float* Aadj = (const float*)d_in[1];
  const float* chbW = (const float*)d_in[2];
  const float* bn1g = (const float*)d_in[3];
  const float* bn1b = (const float*)d_in[4];
  const float* bn2g = (const float*)d_in[5];
  const float* bn2b = (const float*)d_in[6];
  const float* Wq   = (const float*)d_in[7];
  const float* Wk   = (const float*)d_in[8];
  const float* Wv   = (const float*)d_in[9];
  const float* Wf   = (const float*)d_in[10];
  const float* bfv  = (const float*)d_in[11];
  const float* lng  = (const float*)d_in[12];
  const float* lnb  = (const float*)d_in[13];
  const float* Wih  = (const float*)d_in[14];
  const float* Whh  = (const float*)d_in[15];
  const float* bih  = (const float*)d_in[16];
  const float* bhh  = (const float*)d_in[17];
  const float* linW = (const float*)d_in[18];
  const float* linb = (const float*)d_in[19];
  const float* clsW = (const float*)d_in[20];
  const float* clsb = (const float*)d_in[21];

  char* ws = (char*)d_ws;
  u16*   Rb    = (u16*)(ws + OFF_A);
  u16*   OUTB  = (u16*)(ws + OFF_A);
  u16*   YSEQ  = (u16*)(ws + OFF_B);
  u16*   QKV   = (u16*)(ws + OFF_C);
  u16*   CTX   = (u16*)(ws + OFF_D);
  u16*   HLN   = (u16*)(ws + OFF_D);
  u16*   WqkvT = (u16*)(ws + OFF_E);
  u16*   WfT   = (u16*)(ws + OFF_WFT);
  u16*   WihT  = (u16*)(ws + OFF_WIH);
  u16*   Tcat  = (u16*)(ws + OFF_TC);     // overlays Lhat+b1p (written after bn1_fin)
  u16*   WTg   = (u16*)(ws + OFF_WT2);    // overlays QKV region (dead before QKV GEMM)
  float* b1p   = (float*)(ws + OFF_B1P);
  float* b1s   = (float*)(ws + OFF_B1S);
  float* b2p   = (float*)(ws + OFF_B2P);
  float* b2s   = (float*)(ws + OFF_B2S);
  float* GI    = (float*)(ws + OFF_GI);
  float* OUTF  = (float*)(ws + OFF_OUTF);

  wtrans_kernel<<<dim3(32,32,4), 256, 0, stream>>>(Wq, Wk, Wv, Wf, WqkvT, WfT);
  wih_kernel<<<dim3(256), 256, 0, stream>>>(Wih, WihT);
  bn1_part_kernel<<<dim3(32,64), 256, 0, stream>>>(x, b1p);
  bn1_fin_kernel<<<dim3(32), 256, 0, stream>>>(b1p, bn1g, bn1b, b1s);
  lap2_kernel<<<dim3(32), 256, 0, stream>>>(Aadj, chbW, Tcat, WTg);   // after bn1_fin (Tcat overlays b1p)
  cheby_kernel<<<dim3(2048), 256, 0, stream>>>(x, Tcat, WTg, b1s, Rb, b2p);
  bn2_fin_kernel<<<dim3(32), 256, 0, stream>>>(b2p, bn2g, bn2b, b2s);
  bn2apply_kernel<<<dim3(16384), 256, 0, stream>>>(Rb, b2s, YSEQ);
  gemm256_kernel<0><<<dim3(1536), 512, 0, stream>>>(YSEQ, WqkvT, (void*)QKV, 16384, 6144, 2048);
  attn_kernel<<<dim3(2048), 256, 0, stream>>>(QKV, CTX);
  gemm256_kernel<0><<<dim3(512), 512, 0, stream>>>(CTX, WfT, (void*)OUTB, 16384, 2048, 2048);
  ln_kernel<<<dim3(16384), 256, 0, stream>>>(OUTB, YSEQ, bfv, lng, lnb, HLN);
  gemm_bt_kernel<1><<<dim3(256), 256, 0, stream>>>(HLN, WihT, (void*)GI, 16384, 256, 2048);
  gru_kernel<<<dim3(512), 256, 0, stream>>>(GI, Whh, bih, bhh, OUTF);
  head_kernel<<<dim3(512), 256, 0, stream>>>(OUTF, linW, linb, clsW, clsb, (float*)d_out);
}

// Round 5
// 945.561 us; speedup vs baseline: 6.3948x; 1.0388x over previous
//
#include <hip/hip_runtime.h>
#include <hip/hip_bf16.h>

typedef unsigned short u16;
typedef __attribute__((ext_vector_type(8))) short short8;   // 8 x bf16 (4 VGPRs)
typedef __attribute__((ext_vector_type(4))) short short4_;  // 4 x bf16
typedef __attribute__((ext_vector_type(4))) float f32x4;

// ---------------- helpers ----------------
__device__ __forceinline__ u16 f2bf(float f){
  union { float fv; unsigned int u; } v; v.fv = f;
  unsigned int u = v.u;
  u = u + 0x7FFFu + ((u >> 16) & 1u);   // RNE
  return (u16)(u >> 16);
}
__device__ __forceinline__ float bf2f(u16 h){
  union { unsigned int u; float fv; } v; v.u = ((unsigned int)h) << 16; return v.fv;
}
__device__ __forceinline__ float sigmoidf_(float x){ return 1.f/(1.f + __expf(-x)); }
__device__ __forceinline__ float tanhf_(float x){ return 2.f/(1.f + __expf(-2.f*x)) - 1.f; }

__device__ __forceinline__ void gload16(const void* g, void* l){
  __builtin_amdgcn_global_load_lds(
      (const __attribute__((address_space(1))) void*)g,
      (__attribute__((address_space(3))) void*)l, 16, 0, 0);
}
__device__ __forceinline__ f32x4 mfma_bf16(short8 a, short8 b, f32x4 c){
  return __builtin_amdgcn_mfma_f32_16x16x32_bf16(a, b, c, 0, 0, 0);
}

#define ASM_VMCNT2 asm volatile("s_waitcnt vmcnt(2)" ::: "memory")
#define ASM_VMCNT0 asm volatile("s_waitcnt vmcnt(0)" ::: "memory")
#define ASM_LGK0   asm volatile("s_waitcnt lgkmcnt(0)" ::: "memory")
#define SCHB       __builtin_amdgcn_sched_barrier(0)
#define SBAR       do { asm volatile("" ::: "memory"); __builtin_amdgcn_s_barrier(); asm volatile("" ::: "memory"); } while(0)

// ---------------- workspace layout (bytes) ----------------
constexpr size_t OFF_A    = 0;                       // R bf16 [32][512][64][32] ; later: attn-out bf16 [16384][2048]
constexpr size_t OFF_B    = 67108864;                // y_seq bf16 [16384][2048]
constexpr size_t OFF_C    = OFF_B + 67108864;        // WT2 bf16 (pre-GEMM) ; QKV bf16 [16384][6144] ; later GI/OUTF f32
constexpr size_t OFF_D    = OFF_C + 201326592;       // ctx bf16 [16384][2048] ; later: h_ln bf16
constexpr size_t OFF_E    = OFF_D + 67108864;        // WqkvT bf16 [6144][2048]
constexpr size_t OFF_WFT  = OFF_E + 25165824;        // WfT bf16 [2048][2048]
constexpr size_t OFF_WIH  = OFF_WFT + 8388608;       // WihT bf16 [256][2048] (rows 192..255 zero)
constexpr size_t OFF_LHAT = OFF_WIH + 1048576;       // Tcat bf16 [32][64][256]
constexpr size_t OFF_B1P  = OFF_LHAT + 524288;       // bn1 partials f32
constexpr size_t OFF_B1S  = OFF_B1P + 524288;        // bn1 scale/shift f32 [32][32][2]
constexpr size_t OFF_B2P  = OFF_B1S + 8192;          // bn2 partials f32 [32][512][32][2]
constexpr size_t OFF_B2S  = OFF_B2P + 4194304;       // bn2 scale/shift f32 [32][32][2]
constexpr size_t OFF_TC   = OFF_LHAT;                // Tcat bf16 1 MB (after bn1_fin)
constexpr size_t OFF_WT2  = OFF_C;                   // WTg bf16 256 KB (dead before QKV GEMM)
constexpr size_t OFF_GI   = OFF_C;                   // f32 [16384][256]
constexpr size_t OFF_OUTF = OFF_C + 16777216;        // f32 [512][2048]

// ---------------- weight transpose: W[k][n] f32 -> WT[n][k] bf16 ----------------
__global__ __launch_bounds__(256) void wtrans_kernel(const float* __restrict__ Wq, const float* __restrict__ Wk,
                                                     const float* __restrict__ Wv, const float* __restrict__ Wf,
                                                     u16* __restrict__ WqkvT, u16* __restrict__ WfT)
{
  const int k0 = blockIdx.x*64, n0 = blockIdx.y*64, z = blockIdx.z;
  const float* src = (z==0)?Wq:(z==1)?Wk:(z==2)?Wv:Wf;
  u16* dst = (z<3) ? (WqkvT + (size_t)z*2048*2048) : WfT;
  __shared__ float tile[64][65];
  const int c = threadIdx.x & 63, r0 = threadIdx.x >> 6;
#pragma unroll
  for (int i=0;i<16;++i){ int r = r0 + i*4; tile[r][c] = src[(size_t)(k0+r)*2048 + n0 + c]; }
  __syncthreads();
#pragma unroll
  for (int i=0;i<16;++i){ int r = r0 + i*4; dst[(size_t)(n0+r)*2048 + k0 + c] = f2bf(tile[c][r]); }
}

__global__ __launch_bounds__(256) void wih_kernel(const float* __restrict__ Wih, u16* __restrict__ WT)
{
  const int row = blockIdx.x, tid = threadIdx.x;
#pragma unroll
  for (int i=0;i<8;++i){ int col = tid + i*256;
    float v = (row < 192) ? Wih[(size_t)row*2048 + col] : 0.f;
    WT[(size_t)row*2048 + col] = f2bf(v);
  }
}

// ---------------- BN1 stats (two-stage, deterministic) ----------------
__global__ __launch_bounds__(256) void bn1_part_kernel(const float* __restrict__ x, float* __restrict__ part)
{
  const int t = blockIdx.x, sl = blockIdx.y;
  const int f = threadIdx.x & 31, grp = threadIdx.x >> 5;
  float s = 0.f, ss = 0.f;
  for (int bb = 0; bb < 8; ++bb){
    const int b = sl*8 + bb;
    const float* xp = x + ((size_t)(b*32 + t))*2048;
    for (int i = 0; i < 8; ++i){
      int n = i*8 + grp;
      float v = xp[n*32 + f];
      s += v; ss += v*v;
    }
  }
  __shared__ float red[8][32][2];
  red[grp][f][0] = s; red[grp][f][1] = ss;
  __syncthreads();
  if (threadIdx.x < 32){
    float S=0, SS=0;
    for (int g=0; g<8; ++g){ S += red[g][threadIdx.x][0]; SS += red[g][threadIdx.x][1]; }
    size_t o = (((size_t)t*64 + sl)*32 + threadIdx.x)*2;
    part[o] = S; part[o+1] = SS;
  }
}

__global__ __launch_bounds__(256) void bn1_fin_kernel(const float* __restrict__ part, const float* __restrict__ g1,
                                                      const float* __restrict__ b1, float* __restrict__ out)
{
  const int t = blockIdx.x;
  const int f = threadIdx.x & 31, grp = threadIdx.x >> 5;
  float s=0, ss=0;
  for (int sl = grp; sl < 64; sl += 8){
    size_t o = (((size_t)t*64 + sl)*32 + f)*2;
    s += part[o]; ss += part[o+1];
  }
  __shared__ float red[8][32][2];
  red[grp][f][0]=s; red[grp][f][1]=ss;
  __syncthreads();
  if (threadIdx.x < 32){
    float S=0, SS=0;
    for (int g=0; g<8; ++g){ S+=red[g][threadIdx.x][0]; SS+=red[g][threadIdx.x][1]; }
    float mean = S*(1.f/32768.f);
    float var  = SS*(1.f/32768.f) - mean*mean;
    float sc   = g1[t*32+threadIdx.x]*rsqrtf(var + 1e-5f);
    out[(t*32+threadIdx.x)*2]   = sc;
    out[(t*32+threadIdx.x)*2+1] = b1[t*32+threadIdx.x] - mean*sc;
  }
}

// ---------------- lap2: per-t Laplacian + Chebyshev basis T0..T3 (bf16) + W^T (bf16) ----------------
__global__ __launch_bounds__(256) void lap2_kernel(const float* __restrict__ A, const float* __restrict__ chebW,
                                                   u16* __restrict__ Tcat, u16* __restrict__ WTg)
{
  const int t = blockIdx.x, tid = threadIdx.x;
  __shared__ float Ar[64][68];
  __shared__ float L1[64][68];
  __shared__ float T2s[64][68];
  __shared__ float dr[64];
#pragma unroll
  for (int i=0;i<16;++i){ int idx = tid + i*256; int r = idx>>6, c = idx&63;
    float v = A[(size_t)t*4096 + idx]; v = fmaxf(v, 0.f); if (r==c) v = 0.f;
    Ar[r][c] = v; }
  __syncthreads();
  if (tid < 64){
    float s = 0;
    for (int c2=0;c2<64;++c2) s += Ar[tid][c2] + Ar[c2][tid];
    dr[tid] = rsqrtf(s + 1e-10f);
  }
  __syncthreads();
#pragma unroll
  for (int i=0;i<16;++i){ int idx = tid + i*256; int r = idx>>6, c = idx&63;
    L1[r][c] = -(Ar[r][c] + Ar[c][r]) * dr[r] * dr[c];
  }
  __syncthreads();
  const int row = tid >> 2, c0 = (tid & 3) << 4;
  float a2[16];
#pragma unroll
  for (int j=0;j<16;++j) a2[j] = 0.f;
#pragma unroll 4
  for (int m=0;m<64;++m){
    float lv = L1[row][m];
#pragma unroll
    for (int j=0;j<16;++j) a2[j] += lv*L1[m][c0+j];
  }
#pragma unroll
  for (int j=0;j<16;++j) T2s[row][c0+j] = 2.f*a2[j] - ((row==c0+j)?1.f:0.f);
  __syncthreads();
  float a3[16];
#pragma unroll
  for (int j=0;j<16;++j) a3[j] = 0.f;
#pragma unroll 4
  for (int m=0;m<64;++m){
    float lv = L1[row][m];
#pragma unroll
    for (int j=0;j<16;++j) a3[j] += lv*T2s[m][c0+j];
  }
  u16* tb = Tcat + (size_t)t*16384 + row*256;
#pragma unroll
  for (int j=0;j<16;++j){
    int c = c0 + j;
    tb[c]       = f2bf((row==c)?1.f:0.f);
    tb[64 + c]  = f2bf(L1[row][c]);
    tb[128 + c] = f2bf(T2s[row][c]);
    tb[192 + c] = f2bf(2.f*a3[j] - L1[row][c]);
  }
#pragma unroll
  for (int i=0;i<16;++i){
    int idx = tid + i*256;
    int k = idx>>10, f = (idx>>5)&31, fo = idx&31;
    WTg[(size_t)t*4096 + k*1024 + fo*32 + f] = f2bf(chebW[(size_t)t*4096 + idx]);
  }
}

// ---------------- Chebyshev conv via MFMA ----------------
__global__ __launch_bounds__(256) void cheby_kernel(const float* __restrict__ x, const u16* __restrict__ Tcat,
                                                    const u16* __restrict__ WTg, const float* __restrict__ bn1ss,
                                                    u16* __restrict__ Rb, float* __restrict__ bn2p)
{
  const int t = blockIdx.x >> 6, grp = blockIdx.x & 63, b0 = grp*8;
  const int tid = threadIdx.x, wid = tid >> 6, lane = tid & 63;
  const int fr = lane & 15, fk = (lane >> 4) << 3;
  const int cc = lane & 15, cr = (lane >> 4) << 2;

  __shared__ u16 Tc[64][264];
  __shared__ u16 Wt[128][40];
  __shared__ u16 Xs[64][40];
  __shared__ u16 Gt[128][72];
  __shared__ float red[4][32][2];
  __shared__ float scs[64];

  if (tid < 64) scs[tid] = bn1ss[t*64 + tid];
  {
    const u16* src = Tcat + (size_t)t*16384;
#pragma unroll
    for (int i=0;i<8;++i){ int idx = tid + i*256; int r = idx>>5, c8 = (idx&31)<<3;
      *(short8*)&Tc[r][c8] = *(const short8*)&src[r*256 + c8]; }
  }
  {
    const u16* src = WTg + (size_t)t*4096;
#pragma unroll
    for (int i=0;i<2;++i){ int idx = tid + i*256; int r = idx>>2, c8 = (idx&3)<<3;
      *(short8*)&Wt[r][c8] = *(const short8*)&src[r*32 + c8]; }
  }
  __syncthreads();

  for (int bb=0; bb<8; ++bb){
    const int b = b0 + bb;
    {
      const float* xr = x + ((size_t)(b*32 + t))*2048;
      f32x4 v0 = *(const f32x4*)&xr[tid*8];
      f32x4 v1 = *(const f32x4*)&xr[tid*8+4];
      const int fb = (tid*8)&31;
      short8 w;
#pragma unroll
      for (int e=0;e<4;++e){
        w[e]   = (short)f2bf(v0[e]*scs[2*(fb+e)]   + scs[2*(fb+e)+1]);
        w[e+4] = (short)f2bf(v1[e]*scs[2*(fb+4+e)] + scs[2*(fb+4+e)+1]);
      }
      *(short8*)&Xs[tid>>2][(tid&3)<<3] = w;
    }
    __syncthreads();
    {
      f32x4 g[4][2] = {};
      short8 xa[4], wb[2];
#pragma unroll
      for (int m2=0;m2<4;++m2) xa[m2] = *(const short8*)&Xs[m2*16 + fr][fk];
#pragma unroll
      for (int j=0;j<2;++j)    wb[j]  = *(const short8*)&Wt[wid*32 + j*16 + fr][fk];
#pragma unroll
      for (int m2=0;m2<4;++m2)
#pragma unroll
        for (int j=0;j<2;++j) g[m2][j] = mfma_bf16(xa[m2], wb[j], g[m2][j]);
#pragma unroll
      for (int m2=0;m2<4;++m2)
#pragma unroll
        for (int j=0;j<2;++j){
          short4_ q;
#pragma unroll
          for (int r=0;r<4;++r) q[r] = (short)f2bf(g[m2][j][r]);
          *(short4_*)&Gt[wid*32 + j*16 + cc][m2*16 + cr] = q;
        }
    }
    __syncthreads();
    f32x4 racc[2] = {};
#pragma unroll
    for (int ks=0; ks<8; ++ks){
      short8 ta  = *(const short8*)&Tc[wid*16 + fr][ks*32 + fk];
      short8 gb0 = *(const short8*)&Gt[(ks>>1)*32 + fr][(ks&1)*32 + fk];
      short8 gb1 = *(const short8*)&Gt[(ks>>1)*32 + 16 + fr][(ks&1)*32 + fk];
      racc[0] = mfma_bf16(ta, gb0, racc[0]);
      racc[1] = mfma_bf16(ta, gb1, racc[1]);
    }
    u16* rrow = Rb + ((size_t)(t*512 + b))*2048;
    float sev[2], sqv[2];
#pragma unroll
    for (int j=0;j<2;++j){
      float s1=0.f, s2=0.f;
#pragma unroll
      for (int r=0;r<4;++r){
        float v = fmaxf(racc[j][r], 0.f);
        rrow[(wid*16 + cr + r)*32 + j*16 + cc] = f2bf(v);
        s1 += v; s2 += v*v;
      }
      sev[j]=s1; sqv[j]=s2;
    }
#pragma unroll
    for (int j=0;j<2;++j){
      sev[j] += __shfl_xor(sev[j], 16, 64); sev[j] += __shfl_xor(sev[j], 32, 64);
      sqv[j] += __shfl_xor(sqv[j], 16, 64); sqv[j] += __shfl_xor(sqv[j], 32, 64);
    }
    if (lane < 16){
#pragma unroll
      for (int j=0;j<2;++j){ red[wid][j*16+cc][0] = sev[j]; red[wid][j*16+cc][1] = sqv[j]; }
    }
    __syncthreads();
    if (tid < 64){
      int f = tid & 31, c = tid >> 5;
      bn2p[((size_t)(t*512+b)*32 + f)*2 + c] = red[0][f][c]+red[1][f][c]+red[2][f][c]+red[3][f][c];
    }
    __syncthreads();
  }
}

__global__ __launch_bounds__(256) void bn2_fin_kernel(const float* __restrict__ part, const float* __restrict__ g2,
                                                      const float* __restrict__ b2, float* __restrict__ out)
{
  const int t = blockIdx.x;
  const int f = threadIdx.x & 31, grp = threadIdx.x >> 5;
  float s=0, ss=0;
  for (int b = grp; b < 512; b += 8){
    size_t o = ((size_t)(t*512+b)*32 + f)*2;
    s += part[o]; ss += part[o+1];
  }
  __shared__ float red[8][32][2];
  red[grp][f][0]=s; red[grp][f][1]=ss;
  __syncthreads();
  if (threadIdx.x < 32){
    float S=0, SS=0;
    for (int g=0; g<8; ++g){ S+=red[g][threadIdx.x][0]; SS+=red[g][threadIdx.x][1]; }
    float mean = S*(1.f/32768.f);
    float var  = SS*(1.f/32768.f) - mean*mean;
    float scv  = g2[t*32+threadIdx.x]*rsqrtf(var + 1e-5f);
    out[(t*32+threadIdx.x)*2]   = scv;
    out[(t*32+threadIdx.x)*2+1] = b2[t*32+threadIdx.x] - mean*scv;
  }
}

// ---------------- BN2 apply + sigmoid + permute ----------------
__global__ __launch_bounds__(256) void bn2apply_kernel(const u16* __restrict__ Rb, const float* __restrict__ ss,
                                                       u16* __restrict__ YS)
{
  const int t = blockIdx.x >> 9, b = blockIdx.x & 511, tid = threadIdx.x;
  __shared__ float scs[64];
  if (tid < 64) scs[tid] = ss[t*64 + tid];
  __syncthreads();
  const int n = tid >> 2, f0 = (tid & 3) << 3;
  short8 rv = *(const short8*)&Rb[((size_t)(t*512+b))*2048 + tid*8];
  short8 w;
#pragma unroll
  for (int e=0;e<8;++e){
    int f = f0 + e;
    float v = bf2f((u16)rv[e])*scs[f*2] + scs[f*2+1];
    w[e] = (short)f2bf(sigmoidf_(v));
  }
  *(short8*)&YS[((size_t)(b*32 + (n>>1)))*2048 + (n&1)*1024 + t*32 + f0] = w;
}

// ============ 256x256 8-phase bf16 MFMA GEMM (T1..T5) ============
// Block->tile map: xcd = p&7 owns NB/8 consecutive nb panels (B in its L2);
// q = p>>3 sweeps mb-major so ALL XCDs work the same A-rows concurrently
// (A fetched from HBM ~once, then L3-served chip-wide). Requires NB%8==0.
template<int CB>   // 0 -> bf16 C, 1 -> f32 C
__global__ __launch_bounds__(512, 2) void gemm256_kernel(const u16* __restrict__ A, const u16* __restrict__ BT,
                                                         void* __restrict__ C, int M, int N, int K)
{
  __shared__ u16 smem[65536];   // 128 KiB
  const int tid = threadIdx.x, wid = tid >> 6, lane = tid & 63;
  const int MB = M >> 8, NB = N >> 8;
  const int xcd = (int)blockIdx.x & 7, q = (int)blockIdx.x >> 3;
  const int ppx = NB >> 3;                   // panels per XCD
  const int mb = q / ppx, nb = xcd*ppx + q % ppx;
  (void)MB;
  const int m0 = mb << 8, n0g = nb << 8;
  const int nkt = K >> 6;
  const int nit = nkt >> 1;

  const int wr = wid >> 2, wc = wid & 3;
  const int fr = lane & 15, fk = (lane >> 4) << 3;
  const int cz0 = fk ^ ((fr & 7) << 3);
  const int cz1 = (32 + fk) ^ ((fr & 7) << 3);
  const int srow = wid*16 + (lane >> 3);
  const int scol = ((lane & 7) ^ (lane >> 3)) << 3;
  const int bhalf = wc >> 1, brow0 = (wc & 1) << 6;

  f32x4 acc[8][4] = {};
  short8 af[4][2], bg[4][2];

#define STG(PTR, R0, DSTB, TK, H) do { if ((TK) < nkt) { \
  const u16* _g = (PTR) + (size_t)((R0) + ((H)<<7) + srow)*(size_t)K + (size_t)(((TK)<<6) + scol); \
  u16* _d = &smem[(DSTB) + ((H)<<13) + (wid<<10)]; \
  gload16(_g, _d); gload16(_g + ((size_t)K<<3), _d + 512); } } while(0)

#define DSA(BUF, QM) { _Pragma("unroll") for(int m2=0;m2<4;++m2){ \
  const u16* _p = &smem[(BUF) + wr*8192 + (((QM)*64 + m2*16 + fr)<<6)]; \
  af[m2][0] = *(const short8*)(_p + cz0); af[m2][1] = *(const short8*)(_p + cz1); } }

#define DSB(BUF, QN) { _Pragma("unroll") for(int n2=0;n2<2;++n2){ \
  const u16* _p = &smem[(BUF) + 16384 + bhalf*8192 + ((brow0 + (QN)*32 + n2*16 + fr)<<6)]; \
  bg[(QN)*2+n2][0] = *(const short8*)(_p + cz0); bg[(QN)*2+n2][1] = *(const short8*)(_p + cz1); } }

#define MMA(QM, QN) { __builtin_amdgcn_s_setprio(1); \
  _Pragma("unroll") for(int m2=0;m2<4;++m2) _Pragma("unroll") for(int n2=0;n2<2;++n2) { \
    acc[(QM)*4+m2][(QN)*2+n2] = mfma_bf16(af[m2][0], bg[(QN)*2+n2][0], acc[(QM)*4+m2][(QN)*2+n2]); \
    acc[(QM)*4+m2][(QN)*2+n2] = mfma_bf16(af[m2][1], bg[(QN)*2+n2][1], acc[(QM)*4+m2][(QN)*2+n2]); } \
  __builtin_amdgcn_s_setprio(0); }

  STG(A,  m0,  0,     0, 0); STG(A,  m0,  0,     0, 1);
  STG(BT, n0g, 16384, 0, 0); STG(BT, n0g, 16384, 0, 1);
  STG(A,  m0,  32768, 1, 0);
  ASM_VMCNT2; SBAR;

  for (int i = 0; i < nit; ++i){
    const int kb = i*2;
    DSA(0, 0); DSB(0, 0);
    STG(A, m0, 32768, kb+1, 1);
    SBAR; ASM_LGK0; SCHB; MMA(0,0); SBAR;
    DSB(0, 1);
    STG(BT, n0g, 49152, kb+1, 0);
    SBAR; ASM_LGK0; SCHB; MMA(0,1); SBAR;
    DSA(0, 1);
    STG(BT, n0g, 49152, kb+1, 1);
    SBAR; ASM_LGK0; SCHB; MMA(1,0); SBAR;
    STG(A, m0, 0, kb+2, 0);
    if (kb + 2 >= nkt) { ASM_VMCNT0; } else { ASM_VMCNT2; }
    SBAR; MMA(1,1); SBAR;
    DSA(32768, 0); DSB(32768, 0);
    STG(A, m0, 0, kb+2, 1);
    SBAR; ASM_LGK0; SCHB; MMA(0,0); SBAR;
    DSB(32768, 1);
    STG(BT, n0g, 16384, kb+2, 0);
    SBAR; ASM_LGK0; SCHB; MMA(0,1); SBAR;
    DSA(32768, 1);
    STG(BT, n0g, 16384, kb+2, 1);
    SBAR; ASM_LGK0; SCHB; MMA(1,0); SBAR;
    STG(A, m0, 32768, kb+3, 0);
    ASM_VMCNT2;
    SBAR; MMA(1,1); SBAR;
  }

#undef STG
#undef DSA
#undef DSB
#undef MMA

  const int cr = (lane >> 4) << 2, cc = lane & 15;
#pragma unroll
  for (int mf=0; mf<8; ++mf)
#pragma unroll
    for (int nf=0; nf<4; ++nf)
#pragma unroll
      for (int r=0; r<4; ++r){
        const size_t row = (size_t)(m0 + wr*128 + mf*16 + cr + r);
        const size_t col = (size_t)(n0g + wc*64 + nf*16 + cc);
        if (CB == 0) ((u16*)C)[row*(size_t)N + col] = f2bf(acc[mf][nf][r]);
        else        ((float*)C)[row*(size_t)N + col] = acc[mf][nf][r];
      }
}

// ---------------- 128x128 m97-structure GEMM (GRU input, N=256) ----------------
template<int CB>
__global__ __launch_bounds__(256) void gemm_bt_kernel(const u16* __restrict__ A, const u16* __restrict__ BT,
                                                      void* __restrict__ C, int M, int N, int K)
{
  __shared__ u16 As[128*32];
  __shared__ u16 Bs[128*32];
  const int tid = threadIdx.x;
  const int wave = tid >> 6, lane = tid & 63;
  const int mblocks = M >> 7;
  const int mb = blockIdx.x % mblocks;
  const int nb = blockIdx.x / mblocks;
  const int lr = lane >> 2;
  const int lc = (lane & 3) << 3;
  const u16* Ag0 = A  + (size_t)(mb*128 + wave*16 + lr)*K + lc;
  const u16* Bg0 = BT + (size_t)(nb*128 + wave*16 + lr)*K + lc;
  const u16* Ag1 = Ag0 + (size_t)64*K;
  const u16* Bg1 = Bg0 + (size_t)64*K;
  u16* lA0 = &As[(wave*16)*32];
  u16* lA1 = &As[(wave*16+64)*32];
  u16* lB0 = &Bs[(wave*16)*32];
  u16* lB1 = &Bs[(wave*16+64)*32];
  const int wm = (wave >> 1)*64, wn = (wave & 1)*64;
  const int fr = lane & 15, fk = (lane >> 4) << 3;
  f32x4 acc[4][4] = {};
  for (int kt = 0; kt < K; kt += 32){
    __syncthreads();
    gload16(Ag0 + kt, lA0);
    gload16(Ag1 + kt, lA1);
    gload16(Bg0 + kt, lB0);
    gload16(Bg1 + kt, lB1);
    __syncthreads();
    short8 af[4], bfr[4];
#pragma unroll
    for (int i=0;i<4;++i) af[i]  = *(const short8*)&As[(wm + i*16 + fr)*32 + fk];
#pragma unroll
    for (int j=0;j<4;++j) bfr[j] = *(const short8*)&Bs[(wn + j*16 + fr)*32 + fk];
#pragma unroll
    for (int i=0;i<4;++i)
#pragma unroll
      for (int j=0;j<4;++j)
        acc[i][j] = mfma_bf16(af[i], bfr[j], acc[i][j]);
  }
  const int cr = (lane >> 4) << 2, cc = lane & 15;
#pragma unroll
  for (int i=0;i<4;++i)
#pragma unroll
    for (int j=0;j<4;++j)
#pragma unroll
      for (int r=0;r<4;++r){
        const size_t row = (size_t)(mb*128 + wm + i*16 + cr + r);
        const size_t col = (size_t)(nb*128 + wn + j*16 + cc);
        if (CB == 0) ((u16*)C)[row*(size_t)N + col] = f2bf(acc[i][j][r]);
        else        ((float*)C)[row*(size_t)N + col] = acc[i][j][r];
      }
}

// ---------------- attention: per (b,h) block, T=32, dh=512 ----------------
__global__ __launch_bounds__(256) void attn_kernel(const u16* __restrict__ QKV, u16* __restrict__ CTX)
{
  const int b = blockIdx.x >> 2, h = blockIdx.x & 3;
  const int tid = threadIdx.x;
  const int wave = tid >> 6, lane = tid & 63;
  __shared__ float spart[4][32][33];
  __shared__ float sm[32][33];
  __shared__ float rowinv[32];
  __shared__ u16 pb[32][40];
  __shared__ u16 vt[512][40];   // v^T : vt[d][t2]

  { // stage v^T -- coalesced: 8-thread groups read 128B contiguous
    const int t2 = tid >> 3;
    const size_t vbase = ((size_t)(b*32 + t2))*6144 + 4096 + h*512;
#pragma unroll
    for (int i = 0; i < 8; ++i){
      int d0 = i*64 + (tid & 7)*8;
      short8 v8 = *(const short8*)&QKV[vbase + d0];
#pragma unroll
      for (int e = 0; e < 8; ++e) vt[d0+e][t2] = (u16)v8[e];
    }
  }
  const int fr = lane & 15, fk = (lane >> 4) << 3;
  f32x4 sacc[2][2] = {};
  const size_t qrow = ((size_t)(b*32))*6144 + h*512;
#pragma unroll
  for (int kk = 0; kk < 4; ++kk){
    const int kof = wave*128 + kk*32 + fk;
    short8 qf0 = *(const short8*)&QKV[qrow + (size_t)fr*6144 + kof];
    short8 qf1 = *(const short8*)&QKV[qrow + (size_t)(fr+16)*6144 + kof];
    short8 kf0 = *(const short8*)&QKV[qrow + 2048 + (size_t)fr*6144 + kof];
    short8 kf1 = *(const short8*)&QKV[qrow + 2048 + (size_t)(fr+16)*6144 + kof];
    sacc[0][0] = mfma_bf16(qf0, kf0, sacc[0][0]);
    sacc[0][1] = mfma_bf16(qf0, kf1, sacc[0][1]);
    sacc[1][0] = mfma_bf16(qf1, kf0, sacc[1][0]);
    sacc[1][1] = mfma_bf16(qf1, kf1, sacc[1][1]);
  }
  const int cr = (lane >> 4) << 2, cc = lane & 15;
#pragma unroll
  for (int i=0;i<2;++i)
#pragma unroll
    for (int j=0;j<2;++j)
#pragma unroll
      for (int r=0;r<4;++r) spart[wave][i*16+cr+r][j*16+cc] = sacc[i][j][r];
  __syncthreads();
  const float scl = 0.04419417382415922f;  // 512^-0.5
  for (int e = tid; e < 1024; e += 256){
    int r = e >> 5, c = e & 31;
    sm[r][c] = (spart[0][r][c]+spart[1][r][c]+spart[2][r][c]+spart[3][r][c])*scl;
  }
  __syncthreads();
  if (tid < 32){
    float m = -1e30f;
    for (int c=0;c<32;++c) m = fmaxf(m, sm[tid][c]);
    float s = 0;
    for (int c=0;c<32;++c){ float e = __expf(sm[tid][c]-m); sm[tid][c] = e; s += e; }
    rowinv[tid] = 1.f/s;
  }
  __syncthreads();
  for (int e = tid; e < 1024; e += 256){
    int r = e>>5, c = e&31;
    pb[r][c] = f2bf(sm[r][c]*rowinv[r]);
  }
  __syncthreads();
  f32x4 cacc[2][8] = {};
  short8 pf0 = *(const short8*)&pb[fr][fk];
  short8 pf1 = *(const short8*)&pb[fr+16][fk];
#pragma unroll
  for (int j=0;j<8;++j){
    short8 vf = *(const short8*)&vt[wave*128 + j*16 + fr][fk];
    cacc[0][j] = mfma_bf16(pf0, vf, cacc[0][j]);
    cacc[1][j] = mfma_bf16(pf1, vf, cacc[1][j]);
  }
#pragma unroll
  for (int i=0;i<2;++i)
#pragma unroll
    for (int j=0;j<8;++j)
#pragma unroll
      for (int r=0;r<4;++r){
        int t1 = i*16 + cr + r;
        int d  = wave*128 + j*16 + cc;
        CTX[((size_t)(b*32+t1))*2048 + h*512 + d] = f2bf(cacc[i][j][r]);
      }
}

// ---------------- residual + bias + LayerNorm -> h_ln bf16 ----------------
__global__ __launch_bounds__(256) void ln_kernel(const u16* __restrict__ OUT, const u16* __restrict__ YS,
                                                 const float* __restrict__ bfv, const float* __restrict__ lng,
                                                 const float* __restrict__ lnb, u16* __restrict__ HLN)
{
  const int row = blockIdx.x, tid = threadIdx.x;
  const size_t base = (size_t)row*2048 + tid*8;
  short8 o8 = *(const short8*)&OUT[base];
  short8 y8 = *(const short8*)&YS[base];
  float hv[8]; float s = 0;
#pragma unroll
  for (int e=0;e<8;++e){ float v = bf2f((u16)o8[e]) + bf2f((u16)y8[e]) + bfv[tid*8+e]; hv[e]=v; s += v; }
  __shared__ float red[4];
#pragma unroll
  for (int off=32; off; off>>=1) s += __shfl_down(s, off, 64);
  if ((tid&63)==0) red[tid>>6] = s;
  __syncthreads();
  const float mu = (red[0]+red[1]+red[2]+red[3]) * (1.f/2048.f);
  float s2 = 0;
#pragma unroll
  for (int e=0;e<8;++e){ float d = hv[e]-mu; s2 += d*d; }
  __syncthreads();
#pragma unroll
  for (int off=32; off; off>>=1) s2 += __shfl_down(s2, off, 64);
  if ((tid&63)==0) red[tid>>6] = s2;
  __syncthreads();
  const float rstd = rsqrtf((red[0]+red[1]+red[2]+red[3])*(1.f/2048.f) + 1e-5f);
  short8 w;
#pragma unroll
  for (int e=0;e<8;++e) w[e] = (short)f2bf((hv[e]-mu)*rstd*lng[tid*8+e] + lnb[tid*8+e]);
  *(short8*)&HLN[base] = w;
}

// ---------------- GRU scan ----------------
__global__ __launch_bounds__(256) void gru_kernel(const float* __restrict__ GI, const float* __restrict__ Whh,
                                                  const float* __restrict__ bih, const float* __restrict__ bhh,
                                                  float* __restrict__ OUTF)
{
  const int b = blockIdx.x, tid = threadIdx.x;
  __shared__ float w[192*65];
  __shared__ float hprev[64];
  __shared__ float gh[192];
#pragma unroll
  for (int i=0;i<48;++i){ int idx = tid + i*256; w[(idx>>6)*65 + (idx&63)] = Whh[idx]; }
  if (tid < 64) hprev[tid] = 0.f;
  const float bh_ = (tid<192) ? bhh[tid] : 0.f;
  __syncthreads();
  for (int t=0;t<32;++t){
    if (tid < 192){
      float s = bh_;
      const float* wr = &w[tid*65];
#pragma unroll 8
      for (int g=0; g<64; ++g) s += wr[g]*hprev[g];
      gh[tid] = s;
    }
    __syncthreads();
    if (tid < 64){
      const float* gi = GI + ((size_t)(b*32 + t))*256;
      float r  = sigmoidf_(gi[tid]     + bih[tid]     + gh[tid]);
      float z  = sigmoidf_(gi[tid+64]  + bih[tid+64]  + gh[tid+64]);
      float n  = tanhf_(gi[tid+128] + bih[tid+128] + r*gh[tid+128]);
      float hn = (1.f - z)*n + z*hprev[tid];
      hprev[tid] = hn;
      OUTF[(size_t)b*2048 + t*64 + tid] = sigmoidf_(hn);
    }
    __syncthreads();
  }
}

// ---------------- heads ----------------
__global__ __launch_bounds__(256) void head_kernel(const float* __restrict__ OUTF, const float* __restrict__ linW,
                                                   const float* __restrict__ linb, const float* __restrict__ clsW,
                                                   const float* __restrict__ clsb, float* __restrict__ outp)
{
  const int b = blockIdx.x, tid = threadIdx.x;
  __shared__ float row[2048];
  __shared__ float pr[128];
  __shared__ float part[256];
  __shared__ float rn;
#pragma unroll
  for (int i=0;i<8;++i) row[tid + i*256] = OUTF[(size_t)b*2048 + tid + i*256];
  __syncthreads();
  {
    const int j = tid & 127, half = tid >> 7;
    const float* wr = linW + (size_t)j*2048 + half*1024;
    const float* xr = &row[half*1024];
    float s = 0;
    for (int k=0;k<1024;++k) s += xr[k]*wr[k];
    part[tid] = s;
  }
  __syncthreads();
  if (tid < 128){
    float v = part[tid] + part[tid+128] + linb[tid];
    v = sigmoidf_(v);
    pr[tid] = v;
    part[tid] = v*v;
  }
  __syncthreads();
  if (tid == 0){
    float ss = 0;
    for (int i2=0;i2<128;++i2) ss += part[i2];
    rn = 1.f/fmaxf(sqrtf(ss), 1e-12f);
  }
  __syncthreads();
  if (tid < 128) outp[(size_t)b*128 + tid] = pr[tid]*rn;
  if (tid < 192){
    const int c = tid >> 6, l = tid & 63;
    const float* wr = clsW + (size_t)c*2048;
    float s = 0;
    for (int k=l; k<2048; k+=64) s += row[k]*wr[k];
#pragma unroll
    for (int off=32; off; off>>=1) s += __shfl_down(s, off, 64);
    if (l == 0) outp[65536 + (size_t)b*3 + c] = sigmoidf_(s + clsb[c]);
  }
}

// ---------------- launch ----------------
extern "C" void kernel_launch(void* const* d_in, const int* in_sizes, int n_in,
                              void* d_out, int out_size, void* d_ws, size_t ws_size,
                              hipStream_t stream) {
  const float* x    = (const float*)d_in[0];
  const float* Aadj = (const float*)d_in[1];
  const float* chbW = (const float*)d_in[2];
  const float* bn1g = (const float*)d_in[3];
  const float* bn1b = (const float*)d_in[4];
  const float* bn2g = (const float*)d_in[5];
  const float* bn2b = (const float*)d_in[6];
  const float* Wq   = (const float*)d_in[7];
  const float* Wk   = (const float*)d_in[8];
  const float* Wv   = (const float*)d_in[9];
  const float* Wf   = (const float*)d_in[10];
  const float* bfv  = (const float*)d_in[11];
  const float* lng  = (const float*)d_in[12];
  const float* lnb  = (const float*)d_in[13];
  const float* Wih  = (const float*)d_in[14];
  const float* Whh  = (const float*)d_in[15];
  const float* bih  = (const float*)d_in[16];
  const float* bhh  = (const float*)d_in[17];
  const float* linW = (const float*)d_in[18];
  const float* linb = (const float*)d_in[19];
  const float* clsW = (const float*)d_in[20];
  const float* clsb = (const float*)d_in[21];

  char* ws = (char*)d_ws;
  u16*   Rb    = (u16*)(ws + OFF_A);
  u16*   OUTB  = (u16*)(ws + OFF_A);
  u16*   YSEQ  = (u16*)(ws + OFF_B);
  u16*   QKV   = (u16*)(ws + OFF_C);
  u16*   CTX   = (u16*)(ws + OFF_D);
  u16*   HLN   = (u16*)(ws + OFF_D);
  u16*   WqkvT = (u16*)(ws + OFF_E);
  u16*   WfT   = (u16*)(ws + OFF_WFT);
  u16*   WihT  = (u16*)(ws + OFF_WIH);
  u16*   Tcat  = (u16*)(ws + OFF_TC);
  u16*   WTg   = (u16*)(ws + OFF_WT2);
  float* b1p   = (float*)(ws + OFF_B1P);
  float* b1s   = (float*)(ws + OFF_B1S);
  float* b2p   = (float*)(ws + OFF_B2P);
  float* b2s   = (float*)(ws + OFF_B2S);
  float* GI    = (float*)(ws + OFF_GI);
  float* OUTF  = (float*)(ws + OFF_OUTF);

  wtrans_kernel<<<dim3(32,32,4), 256, 0, stream>>>(Wq, Wk, Wv, Wf, WqkvT, WfT);
  wih_kernel<<<dim3(256), 256, 0, stream>>>(Wih, WihT);
  bn1_part_kernel<<<dim3(32,64), 256, 0, stream>>>(x, b1p);
  bn1_fin_kernel<<<dim3(32), 256, 0, stream>>>(b1p, bn1g, bn1b, b1s);
  lap2_kernel<<<dim3(32), 256, 0, stream>>>(Aadj, chbW, Tcat, WTg);
  cheby_kernel<<<dim3(2048), 256, 0, stream>>>(x, Tcat, WTg, b1s, Rb, b2p);
  bn2_fin_kernel<<<dim3(32), 256, 0, stream>>>(b2p, bn2g, bn2b, b2s);
  bn2apply_kernel<<<dim3(16384), 256, 0, stream>>>(Rb, b2s, YSEQ);
  gemm256_kernel<0><<<dim3(1536), 512, 0, stream>>>(YSEQ, WqkvT, (void*)QKV, 16384, 6144, 2048);
  attn_kernel<<<dim3(2048), 256, 0, stream>>>(QKV, CTX);
  gemm256_kernel<0><<<dim3(512), 512, 0, stream>>>(CTX, WfT, (void*)OUTB, 16384, 2048, 2048);
  ln_kernel<<<dim3(16384), 256, 0, stream>>>(OUTB, YSEQ, bfv, lng, lnb, HLN);
  gemm_bt_kernel<1><<<dim3(256), 256, 0, stream>>>(HLN, WihT, (void*)GI, 16384, 256, 2048);
  gru_kernel<<<dim3(512), 256, 0, stream>>>(GI, Whh, bih, bhh, OUTF);
  head_kernel<<<dim3(512), 256, 0, stream>>>(OUTF, linW, linb, clsW, clsb, (float*)d_out);
}